// Round 1
// 2567.680 us; speedup vs baseline: 3.7029x; 3.7029x over previous
//
#include <hip/hip_runtime.h>
#include <math.h>

#define D_  1024
#define T_  1024
#define B_  2
#define H_  16
#define DH_ 64
#define L_  4
#define FF_ 4096
#define V_  32000
#define M_  2048   // B*T tokens

typedef _Float16 f16;
typedef _Float16 f16x8 __attribute__((ext_vector_type(8)));
typedef _Float16 f16x4 __attribute__((ext_vector_type(4)));
typedef float    fx4  __attribute__((ext_vector_type(4)));

// ---------------- fp32 -> fp16 convert (exact-size grid, n % 1024 == 0) ----------------
__global__ __launch_bounds__(256) void f2h_k(const float* __restrict__ in, f16* __restrict__ out) {
    const long i = ((long)blockIdx.x * 256 + threadIdx.x) * 4;
    const float4 v = *(const float4*)(in + i);
    f16x4 o = { (f16)v.x, (f16)v.y, (f16)v.z, (f16)v.w };
    *(f16x4*)(out + i) = o;
}

// ---------------- embedding + positional ----------------
__global__ __launch_bounds__(256) void embed_k(const int* __restrict__ x, const float* __restrict__ emb,
                                               const float* __restrict__ pos, float* __restrict__ h) {
    const long m = blockIdx.x;            // token row 0..2047
    const int  t = threadIdx.x;           // 256 threads * float4 = 1024 floats
    const long tok = x[m];
    const long pt  = m & (T_ - 1);        // m % T
    const float4 e = ((const float4*)(emb + tok * D_))[t];
    const float4 p = ((const float4*)(pos + pt * D_))[t];
    ((float4*)(h + m * D_))[t] = make_float4(e.x + p.x, e.y + p.y, e.z + p.z, e.w + p.w);
}

// ---------------- LayerNorm over D=1024; optional fp32 + fp16 outputs ----------------
__global__ __launch_bounds__(256) void ln_k(const float* __restrict__ x, const float* __restrict__ g,
                                            const float* __restrict__ b, float* __restrict__ of,
                                            f16* __restrict__ oh) {
    const long m = blockIdx.x;
    const int  t = threadIdx.x;
    const int  wave = t >> 6, lane = t & 63;
    __shared__ float red1[4], red2[4];
    const float4 v = ((const float4*)(x + m * D_))[t];
    float s = v.x + v.y + v.z + v.w;
#pragma unroll
    for (int off = 32; off; off >>= 1) s += __shfl_xor(s, off, 64);
    if (lane == 0) red1[wave] = s;
    __syncthreads();
    const float mean = (red1[0] + red1[1] + red1[2] + red1[3]) * (1.0f / 1024.0f);
    const float d0 = v.x - mean, d1 = v.y - mean, d2 = v.z - mean, d3 = v.w - mean;
    float s2 = d0 * d0 + d1 * d1 + d2 * d2 + d3 * d3;
#pragma unroll
    for (int off = 32; off; off >>= 1) s2 += __shfl_xor(s2, off, 64);
    if (lane == 0) red2[wave] = s2;
    __syncthreads();
    const float var  = (red2[0] + red2[1] + red2[2] + red2[3]) * (1.0f / 1024.0f);
    const float rstd = rsqrtf(var + 1e-5f);
    const float4 gv = ((const float4*)g)[t];
    const float4 bv = ((const float4*)b)[t];
    const float o0 = d0 * rstd * gv.x + bv.x;
    const float o1 = d1 * rstd * gv.y + bv.y;
    const float o2 = d2 * rstd * gv.z + bv.z;
    const float o3 = d3 * rstd * gv.w + bv.w;
    if (of) ((float4*)(of + m * D_))[t] = make_float4(o0, o1, o2, o3);
    if (oh) { f16x4 o = { (f16)o0, (f16)o1, (f16)o2, (f16)o3 }; *(f16x4*)(oh + m * D_ + t * 4) = o; }
}

// ---------------- elementwise helpers ----------------
__global__ __launch_bounds__(256) void sub_k(const float* __restrict__ a, const float* __restrict__ b,
                                             f16* __restrict__ o) {   // o = f16(a - b)
    const long i = ((long)blockIdx.x * 256 + threadIdx.x) * 4;
    const float4 va = *(const float4*)(a + i);
    const float4 vb = *(const float4*)(b + i);
    f16x4 o4 = { (f16)(va.x - vb.x), (f16)(va.y - vb.y), (f16)(va.z - vb.z), (f16)(va.w - vb.w) };
    *(f16x4*)(o + i) = o4;
}

__global__ __launch_bounds__(256) void cat_k(const float* __restrict__ p, const float* __restrict__ c,
                                             f16* __restrict__ o) {   // o[m, 0:1024]=p[m], o[m,1024:2048]=c[m]
    const long i = ((long)blockIdx.x * 256 + threadIdx.x) * 4;        // over 2048*2048
    const long m = i >> 11;
    const int  j = (int)(i & 2047);
    const float* src = (j < 1024) ? (p + m * 1024 + j) : (c + m * 1024 + (j - 1024));
    const float4 v = *(const float4*)src;
    f16x4 o4 = { (f16)v.x, (f16)v.y, (f16)v.z, (f16)v.w };
    *(f16x4*)(o + i) = o4;
}

__global__ __launch_bounds__(256) void gate_k(const float* __restrict__ p, const float* __restrict__ c,
                                              const float* __restrict__ gl, f16* __restrict__ o) {
    // o = f16(pred + sigmoid(glin) * corr)
    const long i = ((long)blockIdx.x * 256 + threadIdx.x) * 4;
    const float4 vp = *(const float4*)(p + i);
    const float4 vc = *(const float4*)(c + i);
    const float4 vg = *(const float4*)(gl + i);
    const float s0 = 1.0f / (1.0f + __expf(-vg.x));
    const float s1 = 1.0f / (1.0f + __expf(-vg.y));
    const float s2 = 1.0f / (1.0f + __expf(-vg.z));
    const float s3 = 1.0f / (1.0f + __expf(-vg.w));
    f16x4 o4 = { (f16)(vp.x + s0 * vc.x), (f16)(vp.y + s1 * vc.y),
                 (f16)(vp.z + s2 * vc.z), (f16)(vp.w + s3 * vc.w) };
    *(f16x4*)(o + i) = o4;
}

// ---------------- GEMM: C(M,N) = A(M,K) @ W(N,K)^T [+bias] [+resid] [gelu]; fp32 and/or f16 out ----------------
// m97 structure: 128x128 tile, BK=32, 4 waves 2x2, each wave 4x4 of 16x16x32 MFMA,
// global_load_lds width=16 staging (LDS layout == global lane order, no padding).
__global__ __launch_bounds__(256)
void gemm_bt(const f16* __restrict__ A, const f16* __restrict__ Wt,
             const float* __restrict__ bias, const float* __restrict__ resid,
             float* __restrict__ Cf, f16* __restrict__ Ch,
             int N, int K, int gelu) {
    __shared__ __align__(16) f16 As[128 * 32];
    __shared__ __align__(16) f16 Bs[128 * 32];
    const int tid  = threadIdx.x;
    const int wave = tid >> 6;
    const int lane = tid & 63;
    const long bm = blockIdx.y;
    const long bn = blockIdx.x;
    const int wm = (wave >> 1) * 64;
    const int wn = (wave & 1) * 64;

    fx4 acc[4][4] = {};

    // staging: chunk c = wave*2 + {0,1}; lane covers row c*16 + lane/4, col (lane&3)*8 of the 128x32 tile
    const int c0 = wave * 2;
    const int r0 = c0 * 16 + (lane >> 2);
    const int cc = (lane & 3) * 8;
    const f16* a0 = A  + ((long)bm * 128 + r0) * K + cc;
    const f16* a1 = A  + ((long)bm * 128 + r0 + 16) * K + cc;
    const f16* b0 = Wt + ((long)bn * 128 + r0) * K + cc;
    const f16* b1 = Wt + ((long)bn * 128 + r0 + 16) * K + cc;
    f16* sa0 = &As[c0 * 512];
    f16* sa1 = &As[(c0 + 1) * 512];
    f16* sb0 = &Bs[c0 * 512];
    f16* sb1 = &Bs[(c0 + 1) * 512];

    for (int k0 = 0; k0 < K; k0 += 32) {
        __builtin_amdgcn_global_load_lds((const __attribute__((address_space(1))) void*)(a0 + k0),
                                         (__attribute__((address_space(3))) void*)sa0, 16, 0, 0);
        __builtin_amdgcn_global_load_lds((const __attribute__((address_space(1))) void*)(a1 + k0),
                                         (__attribute__((address_space(3))) void*)sa1, 16, 0, 0);
        __builtin_amdgcn_global_load_lds((const __attribute__((address_space(1))) void*)(b0 + k0),
                                         (__attribute__((address_space(3))) void*)sb0, 16, 0, 0);
        __builtin_amdgcn_global_load_lds((const __attribute__((address_space(1))) void*)(b1 + k0),
                                         (__attribute__((address_space(3))) void*)sb1, 16, 0, 0);
        __syncthreads();   // drains vmcnt before ds_read
        const int koff = (lane >> 4) * 8;
        f16x8 af[4], bf[4];
#pragma unroll
        for (int i = 0; i < 4; ++i) {
            af[i] = *(const f16x8*)&As[(wm + i * 16 + (lane & 15)) * 32 + koff];
            bf[i] = *(const f16x8*)&Bs[(wn + i * 16 + (lane & 15)) * 32 + koff];
        }
#pragma unroll
        for (int i = 0; i < 4; ++i)
#pragma unroll
            for (int j = 0; j < 4; ++j)
                acc[i][j] = __builtin_amdgcn_mfma_f32_16x16x32_f16(af[i], bf[j], acc[i][j], 0, 0, 0);
        __syncthreads();   // protect LDS before next stage
    }

    // epilogue: D row = (lane>>4)*4 + reg, col = lane&15 (verified m89/m91 layout)
    const long gr_base = bm * 128 + wm + (lane >> 4) * 4;
    const long gc_base = bn * 128 + wn + (lane & 15);
#pragma unroll
    for (int i = 0; i < 4; ++i) {
#pragma unroll
        for (int j = 0; j < 4; ++j) {
            const long gc = gc_base + j * 16;
            const float bv = bias ? bias[gc] : 0.0f;
#pragma unroll
            for (int r = 0; r < 4; ++r) {
                const long gr = gr_base + i * 16 + r;
                float v = acc[i][j][r] + bv;
                if (gelu) v = 0.5f * v * (1.0f + erff(v * 0.70710678118654752f));
                else if (resid) v += resid[gr * (long)N + gc];
                if (Cf) Cf[gr * (long)N + gc] = v;
                if (Ch) Ch[gr * (long)N + gc] = (f16)v;
            }
        }
    }
}

// ---------------- flash attention: f16 QKV, fp32 softmax/accum, MFMA 16x16x32 ----------------
// qkv row layout (f16): [3][H][DH] per token. Block = 4 waves = 64 queries of one (b,h).
// grid: (T/64, H, B); big q-tiles launched first (qt descending).
// Fragment layouts (verified by gemm_bt on this HW):
//   A/B frag: lane holds row (lane&15), k = (lane>>4)*8 + j (within a 32-chunk)
//   C/D frag: col = lane&15, row = (lane>>4)*4 + r
__global__ __launch_bounds__(256) void fattn_k(const f16* __restrict__ qkv, float* __restrict__ out) {
    __shared__ __align__(16) f16 Ks[64 * 72];       // K tile [key][d], row stride 72 (pad)
    __shared__ __align__(16) f16 Vt[64 * 72];       // V^T tile [d][key^swz(d)], row stride 72
    __shared__ __align__(16) f16 Pw[4][16 * 72];    // per-wave P tile [q][key], row stride 72
    const int tid  = threadIdx.x;
    const int w    = tid >> 6;
    const int lane = tid & 63;
    const int b  = blockIdx.z, h = blockIdx.y;
    const int qt = (gridDim.x - 1) - blockIdx.x;    // descending tile order
    const int q0w = qt * 64 + w * 16;               // first query of this wave
    const int g  = lane >> 4;                       // 4 lane-groups
    const int lm = lane & 15;

    // Q fragments (held in registers for whole kernel)
    const long qrow = ((long)(b * T_ + q0w + lm)) * (3 * D_) + h * DH_;
    f16x8 af_q[2];
    af_q[0] = *(const f16x8*)(qkv + qrow + g * 8);
    af_q[1] = *(const f16x8*)(qkv + qrow + 32 + g * 8);

    float m_r[4], l_r[4];
    fx4 acc_o[4] = {};     // acc_o[nt][r]: out rows q0w+g*4+r, cols nt*16+lm
#pragma unroll
    for (int r = 0; r < 4; ++r) { m_r[r] = -INFINITY; l_r[r] = 0.0f; }

    // staging coords: 4 threads per key row, each loads 32B (16 f16)
    const int srow = tid >> 2;          // key 0..63 within tile
    const int scol = (tid & 3) * 16;    // d col 0,16,32,48
    const long kbase = ((long)(b * T_)) * (3 * D_) + D_ + h * DH_ + scol;
    const long vbase = kbase + D_;

    const int nkb = qt + 1;
    for (int it = 0; it < nkb; ++it) {
        const int kb = it * 64;
        __syncthreads();    // previous compute done before overwriting K/V tiles
        {
            const f16* ksrc = qkv + kbase + (long)(kb + srow) * (3 * D_);
            f16x8 k0 = *(const f16x8*)(ksrc);
            f16x8 k1 = *(const f16x8*)(ksrc + 8);
            *(f16x8*)&Ks[srow * 72 + scol]     = k0;
            *(f16x8*)&Ks[srow * 72 + scol + 8] = k1;
            const f16* vsrc = qkv + vbase + (long)(kb + srow) * (3 * D_);
            f16x8 v0 = *(const f16x8*)(vsrc);
            f16x8 v1 = *(const f16x8*)(vsrc + 8);
            // transposed scatter with XOR swizzle on key to spread banks
#pragma unroll
            for (int i = 0; i < 8; ++i) {
                const int d = scol + i;
                Vt[d * 72 + (srow ^ (((d >> 2) & 7) << 3))] = v0[i];
            }
#pragma unroll
            for (int i = 0; i < 8; ++i) {
                const int d = scol + 8 + i;
                Vt[d * 72 + (srow ^ (((d >> 2) & 7) << 3))] = v1[i];
            }
        }
        __syncthreads();    // staging visible

        // QK^T: S tiles (16q x 16k) for 4 key sub-tiles
        fx4 sc[4];
#pragma unroll
        for (int kt = 0; kt < 4; ++kt) {
            fx4 c = {};
#pragma unroll
            for (int kk = 0; kk < 2; ++kk) {
                f16x8 bf = *(const f16x8*)&Ks[(kt * 16 + lm) * 72 + kk * 32 + g * 8];
                c = __builtin_amdgcn_mfma_f32_16x16x32_f16(af_q[kk], bf, c, 0, 0, 0);
            }
            sc[kt] = c * 0.125f;   // SCALE = DH^-0.5
        }
        // causal mask only possible in the last key block (kb == qt*64)
        if (kb == qt * 64) {
#pragma unroll
            for (int kt = 0; kt < 4; ++kt) {
                const int key_g = kb + kt * 16 + lm;
#pragma unroll
                for (int r = 0; r < 4; ++r)
                    if (key_g > q0w + g * 4 + r) sc[kt][r] = -INFINITY;
            }
        }

        // online softmax; row q=(g*4+r) lives across the 16 lanes with same g
        float mnew[4], pscale[4];
#pragma unroll
        for (int r = 0; r < 4; ++r) {
            float tm = fmaxf(fmaxf(sc[0][r], sc[1][r]), fmaxf(sc[2][r], sc[3][r]));
#pragma unroll
            for (int off = 8; off; off >>= 1) tm = fmaxf(tm, __shfl_xor(tm, off, 64));
            mnew[r]   = fmaxf(m_r[r], tm);
            pscale[r] = __expf(m_r[r] - mnew[r]);   // 0 on first block (m=-inf)
        }
        float psum[4] = {};
#pragma unroll
        for (int kt = 0; kt < 4; ++kt) {
#pragma unroll
            for (int r = 0; r < 4; ++r) {
                const float p = __expf(sc[kt][r] - mnew[r]);   // masked -> 0
                sc[kt][r] = p;
                psum[r] += p;
            }
        }
#pragma unroll
        for (int r = 0; r < 4; ++r) {
#pragma unroll
            for (int off = 8; off; off >>= 1) psum[r] += __shfl_xor(psum[r], off, 64);
            l_r[r] = l_r[r] * pscale[r] + psum[r];
            m_r[r] = mnew[r];
        }
#pragma unroll
        for (int nt = 0; nt < 4; ++nt)
#pragma unroll
            for (int r = 0; r < 4; ++r) acc_o[nt][r] *= pscale[r];

        // P (C layout) -> per-wave LDS [q][key] -> A frags
        f16* P = Pw[w];
#pragma unroll
        for (int kt = 0; kt < 4; ++kt)
#pragma unroll
            for (int r = 0; r < 4; ++r)
                P[(g * 4 + r) * 72 + kt * 16 + lm] = (f16)sc[kt][r];

        // PV: out(16q x 64d) += P(16x64) @ V(64x64)
#pragma unroll
        for (int kc = 0; kc < 2; ++kc) {
            f16x8 ap = *(const f16x8*)&P[lm * 72 + kc * 32 + g * 8];
#pragma unroll
            for (int nt = 0; nt < 4; ++nt) {
                const int d = nt * 16 + lm;
                const int col = (kc * 32 + g * 8) ^ (((d >> 2) & 7) << 3);
                f16x8 bv = *(const f16x8*)&Vt[d * 72 + col];
                acc_o[nt] = __builtin_amdgcn_mfma_f32_16x16x32_f16(ap, bv, acc_o[nt], 0, 0, 0);
            }
        }
    }

    // epilogue: out[(b*T + q)*D + h*64 + nt*16 + lm] = acc / l
    const long obase = ((long)(b * T_ + q0w + g * 4)) * D_ + h * DH_ + lm;
#pragma unroll
    for (int r = 0; r < 4; ++r) {
        const float inv = 1.0f / l_r[r];
#pragma unroll
        for (int nt = 0; nt < 4; ++nt)
            out[obase + (long)r * D_ + nt * 16] = acc_o[nt][r] * inv;
    }
}

// ---------------- host orchestration ----------------
extern "C" void kernel_launch(void* const* d_in, const int* in_sizes, int n_in,
                              void* d_out, int out_size, void* d_ws, size_t ws_size,
                              hipStream_t stream) {
    const int*   x    = (const int*)d_in[0];
    const float* emb  = (const float*)d_in[1];
    const float* pos  = (const float*)d_in[2];
    const float* Wqkv = (const float*)d_in[3];
    const float* bqkv = (const float*)d_in[4];
    const float* Wo   = (const float*)d_in[5];
    const float* bo   = (const float*)d_in[6];
    const float* Wg   = (const float*)d_in[7];
    const float* bg   = (const float*)d_in[8];
    const float* ln1g = (const float*)d_in[9];
    const float* ln1b = (const float*)d_in[10];
    const float* W1   = (const float*)d_in[11];
    const float* b1   = (const float*)d_in[12];
    const float* W2   = (const float*)d_in[13];
    const float* b2   = (const float*)d_in[14];
    const float* ln2g = (const float*)d_in[15];
    const float* ln2b = (const float*)d_in[16];
    const float* lnfg = (const float*)d_in[17];
    const float* lnfb = (const float*)d_in[18];
    float* out = (float*)d_out;

    char* ws = (char*)d_ws;
    size_t off = 0;
    auto alloc = [&](size_t bytes) -> void* {
        off = (off + 255) & ~(size_t)255;
        void* p = ws + off;
        off += bytes;
        return p;
    };
    float* h    = (float*)alloc((size_t)M_ * D_ * 4);
    float* n1f  = (float*)alloc((size_t)M_ * D_ * 4);
    float* pred = (float*)alloc((size_t)M_ * D_ * 4);
    float* corr = (float*)alloc((size_t)M_ * D_ * 4);
    float* glin = (float*)alloc((size_t)M_ * D_ * 4);
    f16* qkvh  = (f16*)alloc((size_t)M_ * 3 * D_ * 2);
    f16* ab    = (f16*)alloc((size_t)M_ * D_ * 2);
    f16* catb  = (f16*)alloc((size_t)M_ * 2 * D_ * 2);
    f16* ffh   = (f16*)alloc((size_t)M_ * FF_ * 2);
    f16* embh  = (f16*)alloc((size_t)V_ * D_ * 2);
    f16* wqkvh = (f16*)alloc((size_t)L_ * 2 * 3 * D_ * D_ * 2);
    f16* woh   = (f16*)alloc((size_t)L_ * D_ * D_ * 2);
    f16* wgh   = (f16*)alloc((size_t)L_ * D_ * 2 * D_ * 2);
    f16* w1h   = (f16*)alloc((size_t)L_ * FF_ * D_ * 2);
    f16* w2h   = (f16*)alloc((size_t)L_ * D_ * FF_ * 2);

    auto cvt = [&](const float* src, f16* dst, long n) {
        f2h_k<<<dim3((unsigned)(n / 1024)), dim3(256), 0, stream>>>(src, dst);
    };
    cvt(emb,  embh,  (long)V_ * D_);
    cvt(Wqkv, wqkvh, (long)L_ * 2 * 3 * D_ * D_);
    cvt(Wo,   woh,   (long)L_ * D_ * D_);
    cvt(Wg,   wgh,   (long)L_ * D_ * 2 * D_);
    cvt(W1,   w1h,   (long)L_ * FF_ * D_);
    cvt(W2,   w2h,   (long)L_ * D_ * FF_);

    embed_k<<<dim3(M_), dim3(256), 0, stream>>>(x, emb, pos, h);

    auto gemm = [&](const f16* A, const f16* Wt, const float* bias, const float* resid,
                    float* Cf, f16* Ch, int N, int K, int gelu) {
        gemm_bt<<<dim3(N / 128, M_ / 128), dim3(256), 0, stream>>>(A, Wt, bias, resid, Cf, Ch, N, K, gelu);
    };

    for (int l = 0; l < L_; ++l) {
        ln_k<<<dim3(M_), 256, 0, stream>>>(h, ln1g + l * D_, ln1b + l * D_, n1f, ab);
        gemm(ab, wqkvh + (size_t)(l * 2 + 0) * 3 * D_ * D_, bqkv + (l * 2 + 0) * 3 * D_,
             nullptr, nullptr, qkvh, 3 * D_, D_, 0);
        fattn_k<<<dim3(T_ / 64, H_, B_), 256, 0, stream>>>(qkvh, pred);
        sub_k<<<dim3(M_ * D_ / 1024), 256, 0, stream>>>(n1f, pred, ab);
        gemm(ab, wqkvh + (size_t)(l * 2 + 1) * 3 * D_ * D_, bqkv + (l * 2 + 1) * 3 * D_,
             nullptr, nullptr, qkvh, 3 * D_, D_, 0);
        fattn_k<<<dim3(T_ / 64, H_, B_), 256, 0, stream>>>(qkvh, corr);
        cat_k<<<dim3(M_ * 2 * D_ / 1024), 256, 0, stream>>>(pred, corr, catb);
        gemm(catb, wgh + (size_t)l * D_ * 2 * D_, bg + l * D_, nullptr, glin, nullptr, D_, 2 * D_, 0);
        gate_k<<<dim3(M_ * D_ / 1024), 256, 0, stream>>>(pred, corr, glin, ab);
        gemm(ab, woh + (size_t)l * D_ * D_, bo + l * D_, h, h, nullptr, D_, D_, 0);
        ln_k<<<dim3(M_), 256, 0, stream>>>(h, ln2g + l * D_, ln2b + l * D_, nullptr, ab);
        gemm(ab, w1h + (size_t)l * FF_ * D_, b1 + l * FF_, nullptr, nullptr, ffh, FF_, D_, 1);
        gemm(ffh, w2h + (size_t)l * D_ * FF_, b2 + l * D_, h, h, nullptr, D_, FF_, 0);
    }
    ln_k<<<dim3(M_), 256, 0, stream>>>(h, lnfg, lnfb, nullptr, ab);
    gemm(ab, embh, nullptr, nullptr, out, nullptr, V_, D_, 0);
}

// Round 3
// 2339.263 us; speedup vs baseline: 4.0644x; 1.0976x over previous
//
#include <hip/hip_runtime.h>
#include <math.h>

#define D_  1024
#define T_  1024
#define B_  2
#define H_  16
#define DH_ 64
#define L_  4
#define FF_ 4096
#define V_  32000
#define M_  2048   // B*T tokens

typedef _Float16 f16;
typedef _Float16 f16x8 __attribute__((ext_vector_type(8)));
typedef _Float16 f16x4 __attribute__((ext_vector_type(4)));
typedef float    fx4  __attribute__((ext_vector_type(4)));

// ---------------- fp32 -> fp16 convert (exact-size grid, n % 1024 == 0) ----------------
__global__ __launch_bounds__(256) void f2h_k(const float* __restrict__ in, f16* __restrict__ out) {
    const long i = ((long)blockIdx.x * 256 + threadIdx.x) * 4;
    const float4 v = *(const float4*)(in + i);
    f16x4 o = { (f16)v.x, (f16)v.y, (f16)v.z, (f16)v.w };
    *(f16x4*)(out + i) = o;
}

// ---------------- embedding + positional ----------------
__global__ __launch_bounds__(256) void embed_k(const int* __restrict__ x, const float* __restrict__ emb,
                                               const float* __restrict__ pos, float* __restrict__ h) {
    const long m = blockIdx.x;            // token row 0..2047
    const int  t = threadIdx.x;           // 256 threads * float4 = 1024 floats
    const long tok = x[m];
    const long pt  = m & (T_ - 1);        // m % T
    const float4 e = ((const float4*)(emb + tok * D_))[t];
    const float4 p = ((const float4*)(pos + pt * D_))[t];
    ((float4*)(h + m * D_))[t] = make_float4(e.x + p.x, e.y + p.y, e.z + p.z, e.w + p.w);
}

// ---------------- LayerNorm over D=1024; optional fp32 + fp16 outputs ----------------
__global__ __launch_bounds__(256) void ln_k(const float* __restrict__ x, const float* __restrict__ g,
                                            const float* __restrict__ b, float* __restrict__ of,
                                            f16* __restrict__ oh) {
    const long m = blockIdx.x;
    const int  t = threadIdx.x;
    const int  wave = t >> 6, lane = t & 63;
    __shared__ float red1[4], red2[4];
    const float4 v = ((const float4*)(x + m * D_))[t];
    float s = v.x + v.y + v.z + v.w;
#pragma unroll
    for (int off = 32; off; off >>= 1) s += __shfl_xor(s, off, 64);
    if (lane == 0) red1[wave] = s;
    __syncthreads();
    const float mean = (red1[0] + red1[1] + red1[2] + red1[3]) * (1.0f / 1024.0f);
    const float d0 = v.x - mean, d1 = v.y - mean, d2 = v.z - mean, d3 = v.w - mean;
    float s2 = d0 * d0 + d1 * d1 + d2 * d2 + d3 * d3;
#pragma unroll
    for (int off = 32; off; off >>= 1) s2 += __shfl_xor(s2, off, 64);
    if (lane == 0) red2[wave] = s2;
    __syncthreads();
    const float var  = (red2[0] + red2[1] + red2[2] + red2[3]) * (1.0f / 1024.0f);
    const float rstd = rsqrtf(var + 1e-5f);
    const float4 gv = ((const float4*)g)[t];
    const float4 bv = ((const float4*)b)[t];
    const float o0 = d0 * rstd * gv.x + bv.x;
    const float o1 = d1 * rstd * gv.y + bv.y;
    const float o2 = d2 * rstd * gv.z + bv.z;
    const float o3 = d3 * rstd * gv.w + bv.w;
    if (of) ((float4*)(of + m * D_))[t] = make_float4(o0, o1, o2, o3);
    if (oh) { f16x4 o = { (f16)o0, (f16)o1, (f16)o2, (f16)o3 }; *(f16x4*)(oh + m * D_ + t * 4) = o; }
}

// ---------------- elementwise helpers ----------------
__global__ __launch_bounds__(256) void sub_k(const float* __restrict__ a, const float* __restrict__ b,
                                             f16* __restrict__ o) {   // o = f16(a - b)
    const long i = ((long)blockIdx.x * 256 + threadIdx.x) * 4;
    const float4 va = *(const float4*)(a + i);
    const float4 vb = *(const float4*)(b + i);
    f16x4 o4 = { (f16)(va.x - vb.x), (f16)(va.y - vb.y), (f16)(va.z - vb.z), (f16)(va.w - vb.w) };
    *(f16x4*)(o + i) = o4;
}

__global__ __launch_bounds__(256) void cat_k(const float* __restrict__ p, const float* __restrict__ c,
                                             f16* __restrict__ o) {   // o[m, 0:1024]=p[m], o[m,1024:2048]=c[m]
    const long i = ((long)blockIdx.x * 256 + threadIdx.x) * 4;        // over 2048*2048
    const long m = i >> 11;
    const int  j = (int)(i & 2047);
    const float* src = (j < 1024) ? (p + m * 1024 + j) : (c + m * 1024 + (j - 1024));
    const float4 v = *(const float4*)src;
    f16x4 o4 = { (f16)v.x, (f16)v.y, (f16)v.z, (f16)v.w };
    *(f16x4*)(o + i) = o4;
}

__global__ __launch_bounds__(256) void gate_k(const float* __restrict__ p, const float* __restrict__ c,
                                              const float* __restrict__ gl, f16* __restrict__ o) {
    // o = f16(pred + sigmoid(glin) * corr)
    const long i = ((long)blockIdx.x * 256 + threadIdx.x) * 4;
    const float4 vp = *(const float4*)(p + i);
    const float4 vc = *(const float4*)(c + i);
    const float4 vg = *(const float4*)(gl + i);
    const float s0 = 1.0f / (1.0f + __expf(-vg.x));
    const float s1 = 1.0f / (1.0f + __expf(-vg.y));
    const float s2 = 1.0f / (1.0f + __expf(-vg.z));
    const float s3 = 1.0f / (1.0f + __expf(-vg.w));
    f16x4 o4 = { (f16)(vp.x + s0 * vc.x), (f16)(vp.y + s1 * vc.y),
                 (f16)(vp.z + s2 * vc.z), (f16)(vp.w + s3 * vc.w) };
    *(f16x4*)(o + i) = o4;
}

// ---------------- GEMM: C(M,N) = A(M,K) @ W(N,K)^T [+bias] [+resid] [gelu]; fp32 and/or f16 out ----------------
// m97 structure: 128xBN tile, BK=32, 4 waves 2x2, global_load_lds width=16 staging.
// Block remap: chunked XCD swizzle (bijective, nwg%8==0 for all grids here) + bm-fastest
// decomposition, so each XCD owns a contiguous range of bn panels -> each B panel is
// fetched by exactly one XCD L2 (was 8x duplicate fetch: 550MB vs 70MB ideal on vocab GEMM).
template<int BN>
__global__ __launch_bounds__(256)
void gemm_bt(const f16* __restrict__ A, const f16* __restrict__ Wt,
             const float* __restrict__ bias, const float* __restrict__ resid,
             float* __restrict__ Cf, f16* __restrict__ Ch,
             int N, int K, int gelu) {
    __shared__ __align__(16) f16 As[128 * 32];
    __shared__ __align__(16) f16 Bs[BN * 32];
    const int tid  = threadIdx.x;
    const int wave = tid >> 6;
    const int lane = tid & 63;

    // block remap: linear id -> chunked XCD swizzle -> bm-fastest
    const int nbm = gridDim.y;           // M/128
    const int nbn = gridDim.x;           // N/BN
    int bi = blockIdx.y * nbn + blockIdx.x;
    const int nwg = nbm * nbn;
    if ((nwg & 7) == 0) bi = (bi & 7) * (nwg >> 3) + (bi >> 3);
    const long bm = bi % nbm;
    const long bn = bi / nbm;

    const int wm = (wave >> 1) * 64;
    const int wn = (wave & 1) * (BN / 2);
    constexpr int NJ = BN / 32;          // 4 for BN=128, 2 for BN=64

    fx4 acc[4][NJ] = {};

    // A staging: chunk c = wave*2 + {0,1}; lane covers row c*16 + lane/4, col (lane&3)*8
    const int c0 = wave * 2;
    const int r0 = c0 * 16 + (lane >> 2);
    const int cc = (lane & 3) * 8;
    const f16* a0 = A + ((long)bm * 128 + r0) * K + cc;
    const f16* a1 = A + ((long)bm * 128 + r0 + 16) * K + cc;
    f16* sa0 = &As[c0 * 512];
    f16* sa1 = &As[(c0 + 1) * 512];

    // B staging: BN/16 chunks of 16 rows
    const f16* b0;
    const f16* b1 = nullptr;
    f16* sb0;
    f16* sb1 = nullptr;
    if constexpr (BN == 128) {
        b0  = Wt + ((long)bn * 128 + r0) * K + cc;
        b1  = Wt + ((long)bn * 128 + r0 + 16) * K + cc;
        sb0 = &Bs[c0 * 512];
        sb1 = &Bs[(c0 + 1) * 512];
    } else {  // BN == 64: one chunk per wave
        b0  = Wt + ((long)bn * 64 + wave * 16 + (lane >> 2)) * K + cc;
        sb0 = &Bs[wave * 512];
    }

    for (int k0 = 0; k0 < K; k0 += 32) {
        __builtin_amdgcn_global_load_lds((const __attribute__((address_space(1))) void*)(a0 + k0),
                                         (__attribute__((address_space(3))) void*)sa0, 16, 0, 0);
        __builtin_amdgcn_global_load_lds((const __attribute__((address_space(1))) void*)(a1 + k0),
                                         (__attribute__((address_space(3))) void*)sa1, 16, 0, 0);
        __builtin_amdgcn_global_load_lds((const __attribute__((address_space(1))) void*)(b0 + k0),
                                         (__attribute__((address_space(3))) void*)sb0, 16, 0, 0);
        if constexpr (BN == 128)
            __builtin_amdgcn_global_load_lds((const __attribute__((address_space(1))) void*)(b1 + k0),
                                             (__attribute__((address_space(3))) void*)sb1, 16, 0, 0);
        __syncthreads();   // drains vmcnt before ds_read
        const int koff = (lane >> 4) * 8;
        f16x8 af[4], bf[NJ];
#pragma unroll
        for (int i = 0; i < 4; ++i)
            af[i] = *(const f16x8*)&As[(wm + i * 16 + (lane & 15)) * 32 + koff];
#pragma unroll
        for (int j = 0; j < NJ; ++j)
            bf[j] = *(const f16x8*)&Bs[(wn + j * 16 + (lane & 15)) * 32 + koff];
#pragma unroll
        for (int i = 0; i < 4; ++i)
#pragma unroll
            for (int j = 0; j < NJ; ++j)
                acc[i][j] = __builtin_amdgcn_mfma_f32_16x16x32_f16(af[i], bf[j], acc[i][j], 0, 0, 0);
        __syncthreads();   // protect LDS before next stage
    }

    // epilogue: D row = (lane>>4)*4 + reg, col = lane&15 (verified m89/m91 layout)
    const long gr_base = bm * 128 + wm + (lane >> 4) * 4;
    const long gc_base = bn * BN + wn + (lane & 15);
#pragma unroll
    for (int i = 0; i < 4; ++i) {
#pragma unroll
        for (int j = 0; j < NJ; ++j) {
            const long gc = gc_base + j * 16;
            const float bv = bias ? bias[gc] : 0.0f;
#pragma unroll
            for (int r = 0; r < 4; ++r) {
                const long gr = gr_base + i * 16 + r;
                float v = acc[i][j][r] + bv;
                if (gelu) v = 0.5f * v * (1.0f + erff(v * 0.70710678118654752f));
                else if (resid) v += resid[gr * (long)N + gc];
                if (Cf) Cf[gr * (long)N + gc] = v;
                if (Ch) Ch[gr * (long)N + gc] = (f16)v;
            }
        }
    }
}

// ---------------- flash attention: f16 QKV, fp32 softmax/accum, MFMA 16x16x32 ----------------
// qkv row layout (f16): [3][H][DH] per token. Block = 4 waves = 64 queries of one (b,h).
// grid: (T/64, H, B); big q-tiles launched first (qt descending).
// Fragment layouts (verified by gemm_bt on this HW):
//   A/B frag: lane holds row (lane&15), k = (lane>>4)*8 + j (within a 32-chunk)
//   C/D frag: col = lane&15, row = (lane>>4)*4 + r
__global__ __launch_bounds__(256) void fattn_k(const f16* __restrict__ qkv, float* __restrict__ out) {
    __shared__ __align__(16) f16 Ks[64 * 72];       // K tile [key][d], row stride 72 (pad)
    __shared__ __align__(16) f16 Vt[64 * 72];       // V^T tile [d][key^swz(d)], row stride 72
    __shared__ __align__(16) f16 Pw[4][16 * 72];    // per-wave P tile [q][key], row stride 72
    const int tid  = threadIdx.x;
    const int w    = tid >> 6;
    const int lane = tid & 63;
    const int b  = blockIdx.z, h = blockIdx.y;
    const int qt = (gridDim.x - 1) - blockIdx.x;    // descending tile order
    const int q0w = qt * 64 + w * 16;               // first query of this wave
    const int g  = lane >> 4;                       // 4 lane-groups
    const int lm = lane & 15;

    // Q fragments (held in registers for whole kernel)
    const long qrow = ((long)(b * T_ + q0w + lm)) * (3 * D_) + h * DH_;
    f16x8 af_q[2];
    af_q[0] = *(const f16x8*)(qkv + qrow + g * 8);
    af_q[1] = *(const f16x8*)(qkv + qrow + 32 + g * 8);

    float m_r[4], l_r[4];
    fx4 acc_o[4] = {};     // acc_o[nt][r]: out rows q0w+g*4+r, cols nt*16+lm
#pragma unroll
    for (int r = 0; r < 4; ++r) { m_r[r] = -INFINITY; l_r[r] = 0.0f; }

    // staging coords: 4 threads per key row, each loads 32B (16 f16)
    const int srow = tid >> 2;          // key 0..63 within tile
    const int scol = (tid & 3) * 16;    // d col 0,16,32,48
    const long kbase = ((long)(b * T_)) * (3 * D_) + D_ + h * DH_ + scol;
    const long vbase = kbase + D_;

    const int nkb = qt + 1;
    for (int it = 0; it < nkb; ++it) {
        const int kb = it * 64;
        __syncthreads();    // previous compute done before overwriting K/V tiles
        {
            const f16* ksrc = qkv + kbase + (long)(kb + srow) * (3 * D_);
            f16x8 k0 = *(const f16x8*)(ksrc);
            f16x8 k1 = *(const f16x8*)(ksrc + 8);
            *(f16x8*)&Ks[srow * 72 + scol]     = k0;
            *(f16x8*)&Ks[srow * 72 + scol + 8] = k1;
            const f16* vsrc = qkv + vbase + (long)(kb + srow) * (3 * D_);
            f16x8 v0 = *(const f16x8*)(vsrc);
            f16x8 v1 = *(const f16x8*)(vsrc + 8);
            // transposed scatter with XOR swizzle on key to spread banks
#pragma unroll
            for (int i = 0; i < 8; ++i) {
                const int d = scol + i;
                Vt[d * 72 + (srow ^ (((d >> 2) & 7) << 3))] = v0[i];
            }
#pragma unroll
            for (int i = 0; i < 8; ++i) {
                const int d = scol + 8 + i;
                Vt[d * 72 + (srow ^ (((d >> 2) & 7) << 3))] = v1[i];
            }
        }
        __syncthreads();    // staging visible

        // QK^T: S tiles (16q x 16k) for 4 key sub-tiles
        fx4 sc[4];
#pragma unroll
        for (int kt = 0; kt < 4; ++kt) {
            fx4 c = {};
#pragma unroll
            for (int kk = 0; kk < 2; ++kk) {
                f16x8 bf = *(const f16x8*)&Ks[(kt * 16 + lm) * 72 + kk * 32 + g * 8];
                c = __builtin_amdgcn_mfma_f32_16x16x32_f16(af_q[kk], bf, c, 0, 0, 0);
            }
            sc[kt] = c * 0.125f;   // SCALE = DH^-0.5
        }
        // causal mask only possible in the last key block (kb == qt*64)
        if (kb == qt * 64) {
#pragma unroll
            for (int kt = 0; kt < 4; ++kt) {
                const int key_g = kb + kt * 16 + lm;
#pragma unroll
                for (int r = 0; r < 4; ++r)
                    if (key_g > q0w + g * 4 + r) sc[kt][r] = -INFINITY;
            }
        }

        // online softmax; row q=(g*4+r) lives across the 16 lanes with same g
        float mnew[4], pscale[4];
#pragma unroll
        for (int r = 0; r < 4; ++r) {
            float tm = fmaxf(fmaxf(sc[0][r], sc[1][r]), fmaxf(sc[2][r], sc[3][r]));
#pragma unroll
            for (int off = 8; off; off >>= 1) tm = fmaxf(tm, __shfl_xor(tm, off, 64));
            mnew[r]   = fmaxf(m_r[r], tm);
            pscale[r] = __expf(m_r[r] - mnew[r]);   // 0 on first block (m=-inf)
        }
        float psum[4] = {};
#pragma unroll
        for (int kt = 0; kt < 4; ++kt) {
#pragma unroll
            for (int r = 0; r < 4; ++r) {
                const float p = __expf(sc[kt][r] - mnew[r]);   // masked -> 0
                sc[kt][r] = p;
                psum[r] += p;
            }
        }
#pragma unroll
        for (int r = 0; r < 4; ++r) {
#pragma unroll
            for (int off = 8; off; off >>= 1) psum[r] += __shfl_xor(psum[r], off, 64);
            l_r[r] = l_r[r] * pscale[r] + psum[r];
            m_r[r] = mnew[r];
        }
#pragma unroll
        for (int nt = 0; nt < 4; ++nt)
#pragma unroll
            for (int r = 0; r < 4; ++r) acc_o[nt][r] *= pscale[r];

        // P (C layout) -> per-wave LDS [q][key] -> A frags
        f16* P = Pw[w];
#pragma unroll
        for (int kt = 0; kt < 4; ++kt)
#pragma unroll
            for (int r = 0; r < 4; ++r)
                P[(g * 4 + r) * 72 + kt * 16 + lm] = (f16)sc[kt][r];

        // PV: out(16q x 64d) += P(16x64) @ V(64x64)
#pragma unroll
        for (int kc = 0; kc < 2; ++kc) {
            f16x8 ap = *(const f16x8*)&P[lm * 72 + kc * 32 + g * 8];
#pragma unroll
            for (int nt = 0; nt < 4; ++nt) {
                const int d = nt * 16 + lm;
                const int col = (kc * 32 + g * 8) ^ (((d >> 2) & 7) << 3);
                f16x8 bv = *(const f16x8*)&Vt[d * 72 + col];
                acc_o[nt] = __builtin_amdgcn_mfma_f32_16x16x32_f16(ap, bv, acc_o[nt], 0, 0, 0);
            }
        }
    }

    // epilogue: out[(b*T + q)*D + h*64 + nt*16 + lm] = acc / l
    const long obase = ((long)(b * T_ + q0w + g * 4)) * D_ + h * DH_ + lm;
#pragma unroll
    for (int r = 0; r < 4; ++r) {
        const float inv = 1.0f / l_r[r];
#pragma unroll
        for (int nt = 0; nt < 4; ++nt)
            out[obase + (long)r * D_ + nt * 16] = acc_o[nt][r] * inv;
    }
}

// ---------------- host orchestration ----------------
extern "C" void kernel_launch(void* const* d_in, const int* in_sizes, int n_in,
                              void* d_out, int out_size, void* d_ws, size_t ws_size,
                              hipStream_t stream) {
    const int*   x    = (const int*)d_in[0];
    const float* emb  = (const float*)d_in[1];
    const float* pos  = (const float*)d_in[2];
    const float* Wqkv = (const float*)d_in[3];
    const float* bqkv = (const float*)d_in[4];
    const float* Wo   = (const float*)d_in[5];
    const float* bo   = (const float*)d_in[6];
    const float* Wg   = (const float*)d_in[7];
    const float* bg   = (const float*)d_in[8];
    const float* ln1g = (const float*)d_in[9];
    const float* ln1b = (const float*)d_in[10];
    const float* W1   = (const float*)d_in[11];
    const float* b1   = (const float*)d_in[12];
    const float* W2   = (const float*)d_in[13];
    const float* b2   = (const float*)d_in[14];
    const float* ln2g = (const float*)d_in[15];
    const float* ln2b = (const float*)d_in[16];
    const float* lnfg = (const float*)d_in[17];
    const float* lnfb = (const float*)d_in[18];
    float* out = (float*)d_out;

    char* ws = (char*)d_ws;
    size_t off = 0;
    auto alloc = [&](size_t bytes) -> void* {
        off = (off + 255) & ~(size_t)255;
        void* p = ws + off;
        off += bytes;
        return p;
    };
    float* h    = (float*)alloc((size_t)M_ * D_ * 4);
    float* n1f  = (float*)alloc((size_t)M_ * D_ * 4);
    float* pred = (float*)alloc((size_t)M_ * D_ * 4);
    float* corr = (float*)alloc((size_t)M_ * D_ * 4);
    float* glin = (float*)alloc((size_t)M_ * D_ * 4);
    f16* qkvh  = (f16*)alloc((size_t)M_ * 3 * D_ * 2);
    f16* ab    = (f16*)alloc((size_t)M_ * D_ * 2);
    f16* catb  = (f16*)alloc((size_t)M_ * 2 * D_ * 2);
    f16* ffh   = (f16*)alloc((size_t)M_ * FF_ * 2);
    f16* embh  = (f16*)alloc((size_t)V_ * D_ * 2);
    f16* wqkvh = (f16*)alloc((size_t)L_ * 2 * 3 * D_ * D_ * 2);
    f16* woh   = (f16*)alloc((size_t)L_ * D_ * D_ * 2);
    f16* wgh   = (f16*)alloc((size_t)L_ * D_ * 2 * D_ * 2);
    f16* w1h   = (f16*)alloc((size_t)L_ * FF_ * D_ * 2);
    f16* w2h   = (f16*)alloc((size_t)L_ * D_ * FF_ * 2);

    auto cvt = [&](const float* src, f16* dst, long n) {
        f2h_k<<<dim3((unsigned)(n / 1024)), dim3(256), 0, stream>>>(src, dst);
    };
    cvt(emb,  embh,  (long)V_ * D_);
    cvt(Wqkv, wqkvh, (long)L_ * 2 * 3 * D_ * D_);
    cvt(Wo,   woh,   (long)L_ * D_ * D_);
    cvt(Wg,   wgh,   (long)L_ * D_ * 2 * D_);
    cvt(W1,   w1h,   (long)L_ * FF_ * D_);
    cvt(W2,   w2h,   (long)L_ * D_ * FF_);

    embed_k<<<dim3(M_), dim3(256), 0, stream>>>(x, emb, pos, h);

    auto gemm = [&](const f16* A, const f16* Wt, const float* bias, const float* resid,
                    float* Cf, f16* Ch, int N, int K, int gelu) {
        if (N <= 1024)
            gemm_bt<64><<<dim3(N / 64, M_ / 128), dim3(256), 0, stream>>>(A, Wt, bias, resid, Cf, Ch, N, K, gelu);
        else
            gemm_bt<128><<<dim3(N / 128, M_ / 128), dim3(256), 0, stream>>>(A, Wt, bias, resid, Cf, Ch, N, K, gelu);
    };

    for (int l = 0; l < L_; ++l) {
        ln_k<<<dim3(M_), 256, 0, stream>>>(h, ln1g + l * D_, ln1b + l * D_, n1f, ab);
        gemm(ab, wqkvh + (size_t)(l * 2 + 0) * 3 * D_ * D_, bqkv + (l * 2 + 0) * 3 * D_,
             nullptr, nullptr, qkvh, 3 * D_, D_, 0);
        fattn_k<<<dim3(T_ / 64, H_, B_), 256, 0, stream>>>(qkvh, pred);
        sub_k<<<dim3(M_ * D_ / 1024), 256, 0, stream>>>(n1f, pred, ab);
        gemm(ab, wqkvh + (size_t)(l * 2 + 1) * 3 * D_ * D_, bqkv + (l * 2 + 1) * 3 * D_,
             nullptr, nullptr, qkvh, 3 * D_, D_, 0);
        fattn_k<<<dim3(T_ / 64, H_, B_), 256, 0, stream>>>(qkvh, corr);
        cat_k<<<dim3(M_ * 2 * D_ / 1024), 256, 0, stream>>>(pred, corr, catb);
        gemm(catb, wgh + (size_t)l * D_ * 2 * D_, bg + l * D_, nullptr, glin, nullptr, D_, 2 * D_, 0);
        gate_k<<<dim3(M_ * D_ / 1024), 256, 0, stream>>>(pred, corr, glin, ab);
        gemm(ab, woh + (size_t)l * D_ * D_, bo + l * D_, h, h, nullptr, D_, D_, 0);
        ln_k<<<dim3(M_), 256, 0, stream>>>(h, ln2g + l * D_, ln2b + l * D_, nullptr, ab);
        gemm(ab, w1h + (size_t)l * FF_ * D_, b1 + l * FF_, nullptr, nullptr, ffh, FF_, D_, 1);
        gemm(ffh, w2h + (size_t)l * D_ * FF_, b2 + l * D_, h, h, nullptr, D_, FF_, 0);
    }
    ln_k<<<dim3(M_), 256, 0, stream>>>(h, lnfg, lnfb, nullptr, ab);
    gemm(ab, embh, nullptr, nullptr, out, nullptr, V_, D_, 0);
}

// Round 4
// 2295.360 us; speedup vs baseline: 4.1422x; 1.0191x over previous
//
#include <hip/hip_runtime.h>
#include <math.h>

#define D_  1024
#define T_  1024
#define B_  2
#define H_  16
#define DH_ 64
#define L_  4
#define FF_ 4096
#define V_  32000
#define M_  2048   // B*T tokens

typedef _Float16 f16;
typedef _Float16 f16x8 __attribute__((ext_vector_type(8)));
typedef _Float16 f16x4 __attribute__((ext_vector_type(4)));
typedef float    fx4  __attribute__((ext_vector_type(4)));

// ---------------- fp32 -> fp16 convert (exact-size grid, n % 1024 == 0) ----------------
__global__ __launch_bounds__(256) void f2h_k(const float* __restrict__ in, f16* __restrict__ out) {
    const long i = ((long)blockIdx.x * 256 + threadIdx.x) * 4;
    const float4 v = *(const float4*)(in + i);
    f16x4 o = { (f16)v.x, (f16)v.y, (f16)v.z, (f16)v.w };
    *(f16x4*)(out + i) = o;
}

// ---------------- embedding + positional ----------------
__global__ __launch_bounds__(256) void embed_k(const int* __restrict__ x, const float* __restrict__ emb,
                                               const float* __restrict__ pos, float* __restrict__ h) {
    const long m = blockIdx.x;            // token row 0..2047
    const int  t = threadIdx.x;           // 256 threads * float4 = 1024 floats
    const long tok = x[m];
    const long pt  = m & (T_ - 1);        // m % T
    const float4 e = ((const float4*)(emb + tok * D_))[t];
    const float4 p = ((const float4*)(pos + pt * D_))[t];
    ((float4*)(h + m * D_))[t] = make_float4(e.x + p.x, e.y + p.y, e.z + p.z, e.w + p.w);
}

// ---------------- LayerNorm over D=1024; optional fp32 + fp16 outputs ----------------
__global__ __launch_bounds__(256) void ln_k(const float* __restrict__ x, const float* __restrict__ g,
                                            const float* __restrict__ b, float* __restrict__ of,
                                            f16* __restrict__ oh) {
    const long m = blockIdx.x;
    const int  t = threadIdx.x;
    const int  wave = t >> 6, lane = t & 63;
    __shared__ float red1[4], red2[4];
    const float4 v = ((const float4*)(x + m * D_))[t];
    float s = v.x + v.y + v.z + v.w;
#pragma unroll
    for (int off = 32; off; off >>= 1) s += __shfl_xor(s, off, 64);
    if (lane == 0) red1[wave] = s;
    __syncthreads();
    const float mean = (red1[0] + red1[1] + red1[2] + red1[3]) * (1.0f / 1024.0f);
    const float d0 = v.x - mean, d1 = v.y - mean, d2 = v.z - mean, d3 = v.w - mean;
    float s2 = d0 * d0 + d1 * d1 + d2 * d2 + d3 * d3;
#pragma unroll
    for (int off = 32; off; off >>= 1) s2 += __shfl_xor(s2, off, 64);
    if (lane == 0) red2[wave] = s2;
    __syncthreads();
    const float var  = (red2[0] + red2[1] + red2[2] + red2[3]) * (1.0f / 1024.0f);
    const float rstd = rsqrtf(var + 1e-5f);
    const float4 gv = ((const float4*)g)[t];
    const float4 bv = ((const float4*)b)[t];
    const float o0 = d0 * rstd * gv.x + bv.x;
    const float o1 = d1 * rstd * gv.y + bv.y;
    const float o2 = d2 * rstd * gv.z + bv.z;
    const float o3 = d3 * rstd * gv.w + bv.w;
    if (of) ((float4*)(of + m * D_))[t] = make_float4(o0, o1, o2, o3);
    if (oh) { f16x4 o = { (f16)o0, (f16)o1, (f16)o2, (f16)o3 }; *(f16x4*)(oh + m * D_ + t * 4) = o; }
}

// ---------------- elementwise helpers ----------------
__global__ __launch_bounds__(256) void sub_k(const float* __restrict__ a, const float* __restrict__ b,
                                             f16* __restrict__ o) {   // o = f16(a - b)
    const long i = ((long)blockIdx.x * 256 + threadIdx.x) * 4;
    const float4 va = *(const float4*)(a + i);
    const float4 vb = *(const float4*)(b + i);
    f16x4 o4 = { (f16)(va.x - vb.x), (f16)(va.y - vb.y), (f16)(va.z - vb.z), (f16)(va.w - vb.w) };
    *(f16x4*)(o + i) = o4;
}

__global__ __launch_bounds__(256) void cat_k(const float* __restrict__ p, const float* __restrict__ c,
                                             f16* __restrict__ o) {   // o[m, 0:1024]=p[m], o[m,1024:2048]=c[m]
    const long i = ((long)blockIdx.x * 256 + threadIdx.x) * 4;        // over 2048*2048
    const long m = i >> 11;
    const int  j = (int)(i & 2047);
    const float* src = (j < 1024) ? (p + m * 1024 + j) : (c + m * 1024 + (j - 1024));
    const float4 v = *(const float4*)src;
    f16x4 o4 = { (f16)v.x, (f16)v.y, (f16)v.z, (f16)v.w };
    *(f16x4*)(o + i) = o4;
}

__global__ __launch_bounds__(256) void gate_k(const float* __restrict__ p, const float* __restrict__ c,
                                              const float* __restrict__ gl, f16* __restrict__ o) {
    // o = f16(pred + sigmoid(glin) * corr)
    const long i = ((long)blockIdx.x * 256 + threadIdx.x) * 4;
    const float4 vp = *(const float4*)(p + i);
    const float4 vc = *(const float4*)(c + i);
    const float4 vg = *(const float4*)(gl + i);
    const float s0 = 1.0f / (1.0f + __expf(-vg.x));
    const float s1 = 1.0f / (1.0f + __expf(-vg.y));
    const float s2 = 1.0f / (1.0f + __expf(-vg.z));
    const float s3 = 1.0f / (1.0f + __expf(-vg.w));
    f16x4 o4 = { (f16)(vp.x + s0 * vc.x), (f16)(vp.y + s1 * vc.y),
                 (f16)(vp.z + s2 * vc.z), (f16)(vp.w + s3 * vc.w) };
    *(f16x4*)(o + i) = o4;
}

// ---------------- GEMM: C(M,N) = A(M,K) @ W(N,K)^T [+bias] [+resid] [gelu]; fp32 and/or f16 out ----------------
// 128xBN tile, BK=32, 4 waves 2x2, global_load_lds width=16 staging.
// TRIPLE-BUFFERED K-tile pipeline with counted vmcnt (T3/T4 mechanism):
//   - at K-tile t, stage t+2 into buf[(t+2)%3]  (that buffer was fully consumed at end of t-1,
//     protected by the closing s_barrier of iteration t-1 -> no WAR race)
//   - s_waitcnt vmcnt(2L) (L = loads/thread/K-tile) -> batch t landed, t+1/t+2 stay IN FLIGHT
//   - raw s_barrier (NOT __syncthreads, which emits vmcnt(0) and drains the pipeline)
//   - ds_read frags -> MFMA -> lgkmcnt(0) -> s_barrier (reads done before t+1 restages this buf)
// Block remap: chunked XCD swizzle + bm-fastest (round 3: FETCH 550->172MB on vocab GEMM).
template<int BN>
__global__ __launch_bounds__(256)
void gemm_bt(const f16* __restrict__ A, const f16* __restrict__ Wt,
             const float* __restrict__ bias, const float* __restrict__ resid,
             float* __restrict__ Cf, f16* __restrict__ Ch,
             int N, int K, int gelu) {
    __shared__ __align__(16) f16 As[3][128 * 32];
    __shared__ __align__(16) f16 Bs[3][BN * 32];
    const int tid  = threadIdx.x;
    const int wave = tid >> 6;
    const int lane = tid & 63;

    // block remap: linear id -> chunked XCD swizzle -> bm-fastest
    const int nbm = gridDim.y;           // M/128
    const int nbn = gridDim.x;           // N/BN
    int bi = blockIdx.y * nbn + blockIdx.x;
    const int nwg = nbm * nbn;
    if ((nwg & 7) == 0) bi = (bi & 7) * (nwg >> 3) + (bi >> 3);
    const long bm = bi % nbm;
    const long bn = bi / nbm;

    const int wm = (wave >> 1) * 64;
    const int wn = (wave & 1) * (BN / 2);
    constexpr int NJ = BN / 32;          // 4 for BN=128, 2 for BN=64

    fx4 acc[4][NJ] = {};

    // A staging: chunk c = wave*2 + {0,1}; lane covers row c*16 + lane/4, col (lane&3)*8
    const int c0 = wave * 2;
    const int r0 = c0 * 16 + (lane >> 2);
    const int cc = (lane & 3) * 8;
    const f16* a0 = A + ((long)bm * 128 + r0) * K + cc;
    const f16* a1 = A + ((long)bm * 128 + r0 + 16) * K + cc;

    // B staging: BN/16 chunks of 16 rows
    const f16* b0;
    const f16* b1 = nullptr;
    if constexpr (BN == 128) {
        b0 = Wt + ((long)bn * 128 + r0) * K + cc;
        b1 = Wt + ((long)bn * 128 + r0 + 16) * K + cc;
    } else {  // BN == 64: one chunk per wave
        b0 = Wt + ((long)bn * 64 + wave * 16 + (lane >> 2)) * K + cc;
    }

    const int NT = K >> 5;               // K-tiles of 32

    auto STAGE = [&](int kt) {
        const int k0 = kt * 32;
        const int bf3 = kt % 3;
        __builtin_amdgcn_global_load_lds((const __attribute__((address_space(1))) void*)(a0 + k0),
                                         (__attribute__((address_space(3))) void*)&As[bf3][c0 * 512], 16, 0, 0);
        __builtin_amdgcn_global_load_lds((const __attribute__((address_space(1))) void*)(a1 + k0),
                                         (__attribute__((address_space(3))) void*)&As[bf3][(c0 + 1) * 512], 16, 0, 0);
        if constexpr (BN == 128) {
            __builtin_amdgcn_global_load_lds((const __attribute__((address_space(1))) void*)(b0 + k0),
                                             (__attribute__((address_space(3))) void*)&Bs[bf3][c0 * 512], 16, 0, 0);
            __builtin_amdgcn_global_load_lds((const __attribute__((address_space(1))) void*)(b1 + k0),
                                             (__attribute__((address_space(3))) void*)&Bs[bf3][(c0 + 1) * 512], 16, 0, 0);
        } else {
            __builtin_amdgcn_global_load_lds((const __attribute__((address_space(1))) void*)(b0 + k0),
                                             (__attribute__((address_space(3))) void*)&Bs[bf3][wave * 512], 16, 0, 0);
        }
    };

    // prologue: two K-tiles in flight before the loop
    STAGE(0);
    if (NT > 1) STAGE(1);

    const int koff = (lane >> 4) * 8;
    for (int t = 0; t < NT; ++t) {
        if (t + 2 < NT) STAGE(t + 2);
        // counted wait: batch t complete for this wave; t+1/t+2 remain in flight.
        const int rem = NT - 1 - t;
        if constexpr (BN == 128) {       // L = 4 loads/thread/K-tile
            if (rem >= 2)      asm volatile("s_waitcnt vmcnt(8)" ::: "memory");
            else if (rem == 1) asm volatile("s_waitcnt vmcnt(4)" ::: "memory");
            else               asm volatile("s_waitcnt vmcnt(0)" ::: "memory");
        } else {                         // L = 3 loads/thread/K-tile
            if (rem >= 2)      asm volatile("s_waitcnt vmcnt(6)" ::: "memory");
            else if (rem == 1) asm volatile("s_waitcnt vmcnt(3)" ::: "memory");
            else               asm volatile("s_waitcnt vmcnt(0)" ::: "memory");
        }
        __builtin_amdgcn_s_barrier();            // all waves' batch-t loads landed
        __builtin_amdgcn_sched_barrier(0);

        const f16* as = As[t % 3];
        const f16* bs = Bs[t % 3];
        f16x8 af[4], bf[NJ];
#pragma unroll
        for (int i = 0; i < 4; ++i)
            af[i] = *(const f16x8*)&as[(wm + i * 16 + (lane & 15)) * 32 + koff];
#pragma unroll
        for (int j = 0; j < NJ; ++j)
            bf[j] = *(const f16x8*)&bs[(wn + j * 16 + (lane & 15)) * 32 + koff];
#pragma unroll
        for (int i = 0; i < 4; ++i)
#pragma unroll
            for (int j = 0; j < NJ; ++j)
                acc[i][j] = __builtin_amdgcn_mfma_f32_16x16x32_f16(af[i], bf[j], acc[i][j], 0, 0, 0);

        asm volatile("s_waitcnt lgkmcnt(0)" ::: "memory");   // ds_reads retired before release
        __builtin_amdgcn_sched_barrier(0);
        __builtin_amdgcn_s_barrier();            // buf[t%3] free for restage at t+1
    }

    // epilogue: D row = (lane>>4)*4 + reg, col = lane&15 (verified m89/m91 layout)
    const long gr_base = bm * 128 + wm + (lane >> 4) * 4;
    const long gc_base = bn * BN + wn + (lane & 15);
#pragma unroll
    for (int i = 0; i < 4; ++i) {
#pragma unroll
        for (int j = 0; j < NJ; ++j) {
            const long gc = gc_base + j * 16;
            const float bv = bias ? bias[gc] : 0.0f;
#pragma unroll
            for (int r = 0; r < 4; ++r) {
                const long gr = gr_base + i * 16 + r;
                float v = acc[i][j][r] + bv;
                if (gelu) v = 0.5f * v * (1.0f + erff(v * 0.70710678118654752f));
                else if (resid) v += resid[gr * (long)N + gc];
                if (Cf) Cf[gr * (long)N + gc] = v;
                if (Ch) Ch[gr * (long)N + gc] = (f16)v;
            }
        }
    }
}

// ---------------- flash attention: f16 QKV, fp32 softmax/accum, MFMA 16x16x32 ----------------
// qkv row layout (f16): [3][H][DH] per token. Block = 4 waves = 64 queries of one (b,h).
// grid: (T/64, H, B); big q-tiles launched first (qt descending).
// Fragment layouts (verified by gemm_bt on this HW):
//   A/B frag: lane holds row (lane&15), k = (lane>>4)*8 + j (within a 32-chunk)
//   C/D frag: col = lane&15, row = (lane>>4)*4 + r
__global__ __launch_bounds__(256) void fattn_k(const f16* __restrict__ qkv, float* __restrict__ out) {
    __shared__ __align__(16) f16 Ks[64 * 72];       // K tile [key][d], row stride 72 (pad)
    __shared__ __align__(16) f16 Vt[64 * 72];       // V^T tile [d][key^swz(d)], row stride 72
    __shared__ __align__(16) f16 Pw[4][16 * 72];    // per-wave P tile [q][key], row stride 72
    const int tid  = threadIdx.x;
    const int w    = tid >> 6;
    const int lane = tid & 63;
    const int b  = blockIdx.z, h = blockIdx.y;
    const int qt = (gridDim.x - 1) - blockIdx.x;    // descending tile order
    const int q0w = qt * 64 + w * 16;               // first query of this wave
    const int g  = lane >> 4;                       // 4 lane-groups
    const int lm = lane & 15;

    // Q fragments (held in registers for whole kernel)
    const long qrow = ((long)(b * T_ + q0w + lm)) * (3 * D_) + h * DH_;
    f16x8 af_q[2];
    af_q[0] = *(const f16x8*)(qkv + qrow + g * 8);
    af_q[1] = *(const f16x8*)(qkv + qrow + 32 + g * 8);

    float m_r[4], l_r[4];
    fx4 acc_o[4] = {};     // acc_o[nt][r]: out rows q0w+g*4+r, cols nt*16+lm
#pragma unroll
    for (int r = 0; r < 4; ++r) { m_r[r] = -INFINITY; l_r[r] = 0.0f; }

    // staging coords: 4 threads per key row, each loads 32B (16 f16)
    const int srow = tid >> 2;          // key 0..63 within tile
    const int scol = (tid & 3) * 16;    // d col 0,16,32,48
    const long kbase = ((long)(b * T_)) * (3 * D_) + D_ + h * DH_ + scol;
    const long vbase = kbase + D_;

    const int nkb = qt + 1;
    for (int it = 0; it < nkb; ++it) {
        const int kb = it * 64;
        __syncthreads();    // previous compute done before overwriting K/V tiles
        {
            const f16* ksrc = qkv + kbase + (long)(kb + srow) * (3 * D_);
            f16x8 k0 = *(const f16x8*)(ksrc);
            f16x8 k1 = *(const f16x8*)(ksrc + 8);
            *(f16x8*)&Ks[srow * 72 + scol]     = k0;
            *(f16x8*)&Ks[srow * 72 + scol + 8] = k1;
            const f16* vsrc = qkv + vbase + (long)(kb + srow) * (3 * D_);
            f16x8 v0 = *(const f16x8*)(vsrc);
            f16x8 v1 = *(const f16x8*)(vsrc + 8);
            // transposed scatter with XOR swizzle on key to spread banks
#pragma unroll
            for (int i = 0; i < 8; ++i) {
                const int d = scol + i;
                Vt[d * 72 + (srow ^ (((d >> 2) & 7) << 3))] = v0[i];
            }
#pragma unroll
            for (int i = 0; i < 8; ++i) {
                const int d = scol + 8 + i;
                Vt[d * 72 + (srow ^ (((d >> 2) & 7) << 3))] = v1[i];
            }
        }
        __syncthreads();    // staging visible

        // QK^T: S tiles (16q x 16k) for 4 key sub-tiles
        fx4 sc[4];
#pragma unroll
        for (int kt = 0; kt < 4; ++kt) {
            fx4 c = {};
#pragma unroll
            for (int kk = 0; kk < 2; ++kk) {
                f16x8 bf = *(const f16x8*)&Ks[(kt * 16 + lm) * 72 + kk * 32 + g * 8];
                c = __builtin_amdgcn_mfma_f32_16x16x32_f16(af_q[kk], bf, c, 0, 0, 0);
            }
            sc[kt] = c * 0.125f;   // SCALE = DH^-0.5
        }
        // causal mask only possible in the last key block (kb == qt*64)
        if (kb == qt * 64) {
#pragma unroll
            for (int kt = 0; kt < 4; ++kt) {
                const int key_g = kb + kt * 16 + lm;
#pragma unroll
                for (int r = 0; r < 4; ++r)
                    if (key_g > q0w + g * 4 + r) sc[kt][r] = -INFINITY;
            }
        }

        // online softmax; row q=(g*4+r) lives across the 16 lanes with same g
        float mnew[4], pscale[4];
#pragma unroll
        for (int r = 0; r < 4; ++r) {
            float tm = fmaxf(fmaxf(sc[0][r], sc[1][r]), fmaxf(sc[2][r], sc[3][r]));
#pragma unroll
            for (int off = 8; off; off >>= 1) tm = fmaxf(tm, __shfl_xor(tm, off, 64));
            mnew[r]   = fmaxf(m_r[r], tm);
            pscale[r] = __expf(m_r[r] - mnew[r]);   // 0 on first block (m=-inf)
        }
        float psum[4] = {};
#pragma unroll
        for (int kt = 0; kt < 4; ++kt) {
#pragma unroll
            for (int r = 0; r < 4; ++r) {
                const float p = __expf(sc[kt][r] - mnew[r]);   // masked -> 0
                sc[kt][r] = p;
                psum[r] += p;
            }
        }
#pragma unroll
        for (int r = 0; r < 4; ++r) {
#pragma unroll
            for (int off = 8; off; off >>= 1) psum[r] += __shfl_xor(psum[r], off, 64);
            l_r[r] = l_r[r] * pscale[r] + psum[r];
            m_r[r] = mnew[r];
        }
#pragma unroll
        for (int nt = 0; nt < 4; ++nt)
#pragma unroll
            for (int r = 0; r < 4; ++r) acc_o[nt][r] *= pscale[r];

        // P (C layout) -> per-wave LDS [q][key] -> A frags
        f16* P = Pw[w];
#pragma unroll
        for (int kt = 0; kt < 4; ++kt)
#pragma unroll
            for (int r = 0; r < 4; ++r)
                P[(g * 4 + r) * 72 + kt * 16 + lm] = (f16)sc[kt][r];

        // PV: out(16q x 64d) += P(16x64) @ V(64x64)
#pragma unroll
        for (int kc = 0; kc < 2; ++kc) {
            f16x8 ap = *(const f16x8*)&P[lm * 72 + kc * 32 + g * 8];
#pragma unroll
            for (int nt = 0; nt < 4; ++nt) {
                const int d = nt * 16 + lm;
                const int col = (kc * 32 + g * 8) ^ (((d >> 2) & 7) << 3);
                f16x8 bv = *(const f16x8*)&Vt[d * 72 + col];
                acc_o[nt] = __builtin_amdgcn_mfma_f32_16x16x32_f16(ap, bv, acc_o[nt], 0, 0, 0);
            }
        }
    }

    // epilogue: out[(b*T + q)*D + h*64 + nt*16 + lm] = acc / l
    const long obase = ((long)(b * T_ + q0w + g * 4)) * D_ + h * DH_ + lm;
#pragma unroll
    for (int r = 0; r < 4; ++r) {
        const float inv = 1.0f / l_r[r];
#pragma unroll
        for (int nt = 0; nt < 4; ++nt)
            out[obase + (long)r * D_ + nt * 16] = acc_o[nt][r] * inv;
    }
}

// ---------------- host orchestration ----------------
extern "C" void kernel_launch(void* const* d_in, const int* in_sizes, int n_in,
                              void* d_out, int out_size, void* d_ws, size_t ws_size,
                              hipStream_t stream) {
    const int*   x    = (const int*)d_in[0];
    const float* emb  = (const float*)d_in[1];
    const float* pos  = (const float*)d_in[2];
    const float* Wqkv = (const float*)d_in[3];
    const float* bqkv = (const float*)d_in[4];
    const float* Wo   = (const float*)d_in[5];
    const float* bo   = (const float*)d_in[6];
    const float* Wg   = (const float*)d_in[7];
    const float* bg   = (const float*)d_in[8];
    const float* ln1g = (const float*)d_in[9];
    const float* ln1b = (const float*)d_in[10];
    const float* W1   = (const float*)d_in[11];
    const float* b1   = (const float*)d_in[12];
    const float* W2   = (const float*)d_in[13];
    const float* b2   = (const float*)d_in[14];
    const float* ln2g = (const float*)d_in[15];
    const float* ln2b = (const float*)d_in[16];
    const float* lnfg = (const float*)d_in[17];
    const float* lnfb = (const float*)d_in[18];
    float* out = (float*)d_out;

    char* ws = (char*)d_ws;
    size_t off = 0;
    auto alloc = [&](size_t bytes) -> void* {
        off = (off + 255) & ~(size_t)255;
        void* p = ws + off;
        off += bytes;
        return p;
    };
    float* h    = (float*)alloc((size_t)M_ * D_ * 4);
    float* n1f  = (float*)alloc((size_t)M_ * D_ * 4);
    float* pred = (float*)alloc((size_t)M_ * D_ * 4);
    float* corr = (float*)alloc((size_t)M_ * D_ * 4);
    float* glin = (float*)alloc((size_t)M_ * D_ * 4);
    f16* qkvh  = (f16*)alloc((size_t)M_ * 3 * D_ * 2);
    f16* ab    = (f16*)alloc((size_t)M_ * D_ * 2);
    f16* catb  = (f16*)alloc((size_t)M_ * 2 * D_ * 2);
    f16* ffh   = (f16*)alloc((size_t)M_ * FF_ * 2);
    f16* embh  = (f16*)alloc((size_t)V_ * D_ * 2);
    f16* wqkvh = (f16*)alloc((size_t)L_ * 2 * 3 * D_ * D_ * 2);
    f16* woh   = (f16*)alloc((size_t)L_ * D_ * D_ * 2);
    f16* wgh   = (f16*)alloc((size_t)L_ * D_ * 2 * D_ * 2);
    f16* w1h   = (f16*)alloc((size_t)L_ * FF_ * D_ * 2);
    f16* w2h   = (f16*)alloc((size_t)L_ * D_ * FF_ * 2);

    auto cvt = [&](const float* src, f16* dst, long n) {
        f2h_k<<<dim3((unsigned)(n / 1024)), dim3(256), 0, stream>>>(src, dst);
    };
    cvt(emb,  embh,  (long)V_ * D_);
    cvt(Wqkv, wqkvh, (long)L_ * 2 * 3 * D_ * D_);
    cvt(Wo,   woh,   (long)L_ * D_ * D_);
    cvt(Wg,   wgh,   (long)L_ * D_ * 2 * D_);
    cvt(W1,   w1h,   (long)L_ * FF_ * D_);
    cvt(W2,   w2h,   (long)L_ * D_ * FF_);

    embed_k<<<dim3(M_), dim3(256), 0, stream>>>(x, emb, pos, h);

    auto gemm = [&](const f16* A, const f16* Wt, const float* bias, const float* resid,
                    float* Cf, f16* Ch, int N, int K, int gelu) {
        if (N <= 1024)
            gemm_bt<64><<<dim3(N / 64, M_ / 128), dim3(256), 0, stream>>>(A, Wt, bias, resid, Cf, Ch, N, K, gelu);
        else
            gemm_bt<128><<<dim3(N / 128, M_ / 128), dim3(256), 0, stream>>>(A, Wt, bias, resid, Cf, Ch, N, K, gelu);
    };

    for (int l = 0; l < L_; ++l) {
        ln_k<<<dim3(M_), 256, 0, stream>>>(h, ln1g + l * D_, ln1b + l * D_, n1f, ab);
        gemm(ab, wqkvh + (size_t)(l * 2 + 0) * 3 * D_ * D_, bqkv + (l * 2 + 0) * 3 * D_,
             nullptr, nullptr, qkvh, 3 * D_, D_, 0);
        fattn_k<<<dim3(T_ / 64, H_, B_), 256, 0, stream>>>(qkvh, pred);
        sub_k<<<dim3(M_ * D_ / 1024), 256, 0, stream>>>(n1f, pred, ab);
        gemm(ab, wqkvh + (size_t)(l * 2 + 1) * 3 * D_ * D_, bqkv + (l * 2 + 1) * 3 * D_,
             nullptr, nullptr, qkvh, 3 * D_, D_, 0);
        fattn_k<<<dim3(T_ / 64, H_, B_), 256, 0, stream>>>(qkvh, corr);
        cat_k<<<dim3(M_ * 2 * D_ / 1024), 256, 0, stream>>>(pred, corr, catb);
        gemm(catb, wgh + (size_t)l * D_ * 2 * D_, bg + l * D_, nullptr, glin, nullptr, D_, 2 * D_, 0);
        gate_k<<<dim3(M_ * D_ / 1024), 256, 0, stream>>>(pred, corr, glin, ab);
        gemm(ab, woh + (size_t)l * D_ * D_, bo + l * D_, h, h, nullptr, D_, D_, 0);
        ln_k<<<dim3(M_), 256, 0, stream>>>(h, ln2g + l * D_, ln2b + l * D_, nullptr, ab);
        gemm(ab, w1h + (size_t)l * FF_ * D_, b1 + l * FF_, nullptr, nullptr, ffh, FF_, D_, 1);
        gemm(ffh, w2h + (size_t)l * D_ * FF_, b2 + l * D_, h, h, nullptr, D_, FF_, 0);
    }
    ln_k<<<dim3(M_), 256, 0, stream>>>(h, lnfg, lnfb, nullptr, ab);
    gemm(ab, embh, nullptr, nullptr, out, nullptr, V_, D_, 0);
}

// Round 8
// 2200.328 us; speedup vs baseline: 4.3211x; 1.0432x over previous
//
#include <hip/hip_runtime.h>
#include <math.h>

#define D_  1024
#define T_  1024
#define B_  2
#define H_  16
#define DH_ 64
#define L_  4
#define FF_ 4096
#define V_  32000
#define M_  2048   // B*T tokens

typedef _Float16 f16;
typedef _Float16 f16x8 __attribute__((ext_vector_type(8)));
typedef _Float16 f16x4 __attribute__((ext_vector_type(4)));
typedef _Float16 f16x2 __attribute__((ext_vector_type(2)));
typedef float    fx4  __attribute__((ext_vector_type(4)));

// ---------------- fp32 -> fp16 convert (exact-size grid, n % 1024 == 0) ----------------
__global__ __launch_bounds__(256) void f2h_k(const float* __restrict__ in, f16* __restrict__ out) {
    const long i = ((long)blockIdx.x * 256 + threadIdx.x) * 4;
    const float4 v = *(const float4*)(in + i);
    f16x4 o = { (f16)v.x, (f16)v.y, (f16)v.z, (f16)v.w };
    *(f16x4*)(out + i) = o;
}

// ---------------- embedding + positional ----------------
__global__ __launch_bounds__(256) void embed_k(const int* __restrict__ x, const float* __restrict__ emb,
                                               const float* __restrict__ pos, float* __restrict__ h) {
    const long m = blockIdx.x;            // token row 0..2047
    const int  t = threadIdx.x;           // 256 threads * float4 = 1024 floats
    const long tok = x[m];
    const long pt  = m & (T_ - 1);        // m % T
    const float4 e = ((const float4*)(emb + tok * D_))[t];
    const float4 p = ((const float4*)(pos + pt * D_))[t];
    ((float4*)(h + m * D_))[t] = make_float4(e.x + p.x, e.y + p.y, e.z + p.z, e.w + p.w);
}

// ---------------- LayerNorm over D=1024; optional fp32 + fp16 outputs ----------------
__global__ __launch_bounds__(256) void ln_k(const float* __restrict__ x, const float* __restrict__ g,
                                            const float* __restrict__ b, float* __restrict__ of,
                                            f16* __restrict__ oh) {
    const long m = blockIdx.x;
    const int  t = threadIdx.x;
    const int  wave = t >> 6, lane = t & 63;
    __shared__ float red1[4], red2[4];
    const float4 v = ((const float4*)(x + m * D_))[t];
    float s = v.x + v.y + v.z + v.w;
#pragma unroll
    for (int off = 32; off; off >>= 1) s += __shfl_xor(s, off, 64);
    if (lane == 0) red1[wave] = s;
    __syncthreads();
    const float mean = (red1[0] + red1[1] + red1[2] + red1[3]) * (1.0f / 1024.0f);
    const float d0 = v.x - mean, d1 = v.y - mean, d2 = v.z - mean, d3 = v.w - mean;
    float s2 = d0 * d0 + d1 * d1 + d2 * d2 + d3 * d3;
#pragma unroll
    for (int off = 32; off; off >>= 1) s2 += __shfl_xor(s2, off, 64);
    if (lane == 0) red2[wave] = s2;
    __syncthreads();
    const float var  = (red2[0] + red2[1] + red2[2] + red2[3]) * (1.0f / 1024.0f);
    const float rstd = rsqrtf(var + 1e-5f);
    const float4 gv = ((const float4*)g)[t];
    const float4 bv = ((const float4*)b)[t];
    const float o0 = d0 * rstd * gv.x + bv.x;
    const float o1 = d1 * rstd * gv.y + bv.y;
    const float o2 = d2 * rstd * gv.z + bv.z;
    const float o3 = d3 * rstd * gv.w + bv.w;
    if (of) ((float4*)(of + m * D_))[t] = make_float4(o0, o1, o2, o3);
    if (oh) { f16x4 o = { (f16)o0, (f16)o1, (f16)o2, (f16)o3 }; *(f16x4*)(oh + m * D_ + t * 4) = o; }
}

// ---------------- elementwise helpers ----------------
__global__ __launch_bounds__(256) void sub_k(const float* __restrict__ a, const float* __restrict__ b,
                                             f16* __restrict__ o) {   // o = f16(a - b)
    const long i = ((long)blockIdx.x * 256 + threadIdx.x) * 4;
    const float4 va = *(const float4*)(a + i);
    const float4 vb = *(const float4*)(b + i);
    f16x4 o4 = { (f16)(va.x - vb.x), (f16)(va.y - vb.y), (f16)(va.z - vb.z), (f16)(va.w - vb.w) };
    *(f16x4*)(o + i) = o4;
}

__global__ __launch_bounds__(256) void cat_k(const float* __restrict__ p, const float* __restrict__ c,
                                             f16* __restrict__ o) {   // o[m, 0:1024]=p[m], o[m,1024:2048]=c[m]
    const long i = ((long)blockIdx.x * 256 + threadIdx.x) * 4;        // over 2048*2048
    const long m = i >> 11;
    const int  j = (int)(i & 2047);
    const float* src = (j < 1024) ? (p + m * 1024 + j) : (c + m * 1024 + (j - 1024));
    const float4 v = *(const float4*)src;
    f16x4 o4 = { (f16)v.x, (f16)v.y, (f16)v.z, (f16)v.w };
    *(f16x4*)(o + i) = o4;
}

__global__ __launch_bounds__(256) void gate_k(const float* __restrict__ p, const float* __restrict__ c,
                                              const float* __restrict__ gl, f16* __restrict__ o) {
    // o = f16(pred + sigmoid(glin) * corr)
    const long i = ((long)blockIdx.x * 256 + threadIdx.x) * 4;
    const float4 vp = *(const float4*)(p + i);
    const float4 vc = *(const float4*)(c + i);
    const float4 vg = *(const float4*)(gl + i);
    const float s0 = 1.0f / (1.0f + __expf(-vg.x));
    const float s1 = 1.0f / (1.0f + __expf(-vg.y));
    const float s2 = 1.0f / (1.0f + __expf(-vg.z));
    const float s3 = 1.0f / (1.0f + __expf(-vg.w));
    f16x4 o4 = { (f16)(vp.x + s0 * vc.x), (f16)(vp.y + s1 * vc.y),
                 (f16)(vp.z + s2 * vc.z), (f16)(vp.w + s3 * vc.w) };
    *(f16x4*)(o + i) = o4;
}

// ---------------- GEMM: C(M,N) = A(M,K) @ W(N,K)^T [+bias] [+resid] [gelu]; fp32 and/or f16 out ----------------
// 128xBN tile, BK=32, 4 waves 2x2, global_load_lds width=16 staging, triple-buffered K pipeline
// with counted vmcnt (round 4).
// LDS BANK-CONFLICT SWIZZLE (T2, both-sides involution, rule 21):
//   logical layout: row-major [row][32 f16], row stride 64B (4 slots of 16B).
//   physical slot p of row r holds logical slot p ^ ((r>>1)&3).
//   - WRITE side: global_load_lds writes lane-linear, so swizzle is realized by pre-permuting
//     the GLOBAL source: lane l loads col slot (l&3)^((l>>3)&3) of row l>>2.
//   - READ side: koff = (g ^ ((lm>>1)&3))*8 -> per 8-lane service phase, granules go
//     {0,4,0,4,...} -> {0,4,1,5,2,6,3,7} (all distinct) = ~conflict-free.
// Block remap: chunked XCD swizzle + bm-fastest (round 3: FETCH 550->172MB on vocab GEMM).
template<int BN>
__global__ __launch_bounds__(256)
void gemm_bt(const f16* __restrict__ A, const f16* __restrict__ Wt,
             const float* __restrict__ bias, const float* __restrict__ resid,
             float* __restrict__ Cf, f16* __restrict__ Ch,
             int N, int K, int gelu) {
    __shared__ __align__(16) f16 As[3][128 * 32];
    __shared__ __align__(16) f16 Bs[3][BN * 32];
    const int tid  = threadIdx.x;
    const int wave = tid >> 6;
    const int lane = tid & 63;

    // block remap: linear id -> chunked XCD swizzle -> bm-fastest
    const int nbm = gridDim.y;           // M/128
    const int nbn = gridDim.x;           // N/BN
    int bi = blockIdx.y * nbn + blockIdx.x;
    const int nwg = nbm * nbn;
    if ((nwg & 7) == 0) bi = (bi & 7) * (nwg >> 3) + (bi >> 3);
    const long bm = bi % nbm;
    const long bn = bi / nbm;

    const int wm = (wave >> 1) * 64;
    const int wn = (wave & 1) * (BN / 2);
    constexpr int NJ = BN / 32;          // 4 for BN=128, 2 for BN=64

    fx4 acc[4][NJ] = {};

    // A staging: chunk c = wave*2 + {0,1}; lane covers row c*16 + lane/4,
    // col slot PRE-SWIZZLED: ((lane&3) ^ ((lane>>3)&3)) * 8  (row bits 1-2 = lane bits 3-4)
    const int c0 = wave * 2;
    const int r0 = c0 * 16 + (lane >> 2);
    const int cc = ((lane & 3) ^ ((lane >> 3) & 3)) * 8;
    const f16* a0 = A + ((long)bm * 128 + r0) * K + cc;
    const f16* a1 = A + ((long)bm * 128 + r0 + 16) * K + cc;

    // B staging: BN/16 chunks of 16 rows (same pre-swizzled slot)
    const f16* b0;
    const f16* b1 = nullptr;
    if constexpr (BN == 128) {
        b0 = Wt + ((long)bn * 128 + r0) * K + cc;
        b1 = Wt + ((long)bn * 128 + r0 + 16) * K + cc;
    } else {  // BN == 64: one chunk per wave
        b0 = Wt + ((long)bn * 64 + wave * 16 + (lane >> 2)) * K + cc;
    }

    const int NT = K >> 5;               // K-tiles of 32

    auto STAGE = [&](int kt) {
        const int k0 = kt * 32;
        const int bf3 = kt % 3;
        __builtin_amdgcn_global_load_lds((const __attribute__((address_space(1))) void*)(a0 + k0),
                                         (__attribute__((address_space(3))) void*)&As[bf3][c0 * 512], 16, 0, 0);
        __builtin_amdgcn_global_load_lds((const __attribute__((address_space(1))) void*)(a1 + k0),
                                         (__attribute__((address_space(3))) void*)&As[bf3][(c0 + 1) * 512], 16, 0, 0);
        if constexpr (BN == 128) {
            __builtin_amdgcn_global_load_lds((const __attribute__((address_space(1))) void*)(b0 + k0),
                                             (__attribute__((address_space(3))) void*)&Bs[bf3][c0 * 512], 16, 0, 0);
            __builtin_amdgcn_global_load_lds((const __attribute__((address_space(1))) void*)(b1 + k0),
                                             (__attribute__((address_space(3))) void*)&Bs[bf3][(c0 + 1) * 512], 16, 0, 0);
        } else {
            __builtin_amdgcn_global_load_lds((const __attribute__((address_space(1))) void*)(b0 + k0),
                                             (__attribute__((address_space(3))) void*)&Bs[bf3][wave * 512], 16, 0, 0);
        }
    };

    // prologue: two K-tiles in flight before the loop
    STAGE(0);
    if (NT > 1) STAGE(1);

    const int lm = lane & 15;
    const int g  = lane >> 4;
    // swizzled read offset: logical slot g lives at physical slot g ^ ((row>>1)&3),
    // and row bits 1-2 = lm bits 1-2 for every fragment row (wm, i*16 are multiples of 16)
    const int koff = (g ^ ((lm >> 1) & 3)) * 8;
    for (int t = 0; t < NT; ++t) {
        if (t + 2 < NT) STAGE(t + 2);
        // counted wait: batch t complete for this wave; t+1/t+2 remain in flight.
        const int rem = NT - 1 - t;
        if constexpr (BN == 128) {       // L = 4 loads/thread/K-tile
            if (rem >= 2)      asm volatile("s_waitcnt vmcnt(8)" ::: "memory");
            else if (rem == 1) asm volatile("s_waitcnt vmcnt(4)" ::: "memory");
            else               asm volatile("s_waitcnt vmcnt(0)" ::: "memory");
        } else {                         // L = 3 loads/thread/K-tile
            if (rem >= 2)      asm volatile("s_waitcnt vmcnt(6)" ::: "memory");
            else if (rem == 1) asm volatile("s_waitcnt vmcnt(3)" ::: "memory");
            else               asm volatile("s_waitcnt vmcnt(0)" ::: "memory");
        }
        __builtin_amdgcn_s_barrier();            // all waves' batch-t loads landed
        __builtin_amdgcn_sched_barrier(0);

        const f16* as = As[t % 3];
        const f16* bs = Bs[t % 3];
        f16x8 af[4], bf[NJ];
#pragma unroll
        for (int i = 0; i < 4; ++i)
            af[i] = *(const f16x8*)&as[(wm + i * 16 + lm) * 32 + koff];
#pragma unroll
        for (int j = 0; j < NJ; ++j)
            bf[j] = *(const f16x8*)&bs[(wn + j * 16 + lm) * 32 + koff];
#pragma unroll
        for (int i = 0; i < 4; ++i)
#pragma unroll
            for (int j = 0; j < NJ; ++j)
                acc[i][j] = __builtin_amdgcn_mfma_f32_16x16x32_f16(af[i], bf[j], acc[i][j], 0, 0, 0);

        asm volatile("s_waitcnt lgkmcnt(0)" ::: "memory");   // ds_reads retired before release
        __builtin_amdgcn_sched_barrier(0);
        __builtin_amdgcn_s_barrier();            // buf[t%3] free for restage at t+1
    }

    // epilogue: D row = (lane>>4)*4 + reg, col = lane&15 (verified m89/m91 layout)
    const long gr_base = bm * 128 + wm + (lane >> 4) * 4;
    const long gc_base = bn * BN + wn + (lane & 15);
#pragma unroll
    for (int i = 0; i < 4; ++i) {
#pragma unroll
        for (int j = 0; j < NJ; ++j) {
            const long gc = gc_base + j * 16;
            const float bv = bias ? bias[gc] : 0.0f;
#pragma unroll
            for (int r = 0; r < 4; ++r) {
                const long gr = gr_base + i * 16 + r;
                float v = acc[i][j][r] + bv;
                if (gelu) v = 0.5f * v * (1.0f + erff(v * 0.70710678118654752f));
                else if (resid) v += resid[gr * (long)N + gc];
                if (Cf) Cf[gr * (long)N + gc] = v;
                if (Ch) Ch[gr * (long)N + gc] = (f16)v;
            }
        }
    }
}

// ---------------- flash attention: f16 QKV, fp32 softmax/accum, MFMA 16x16x32 ----------------
// qkv row layout (f16): [3][H][DH] per token. Block = 4 waves = 64 queries of one (b,h).
// grid: (T/64, H, B); big q-tiles launched first (qt descending).
// Round 5: (a) T14 async-stage split — next tile's K/V loaded into REGISTERS during the
//   compute phase (hides ~300cyc L2 latency under ~1000cyc compute); regs -> LDS at top of
//   next iteration. (b) vectorized V^T scatter: threads own key PAIRS (2 keys x 8 d) and
//   write 8x f16x2 instead of 16x ds_write_b16 (XOR swizzle term is a multiple of 8, so
//   key pairs stay adjacent after swizzle).
__global__ __launch_bounds__(256) void fattn_k(const f16* __restrict__ qkv, float* __restrict__ out) {
    __shared__ __align__(16) f16 Ks[64 * 72];       // K tile [key][d], row stride 72 (pad)
    __shared__ __align__(16) f16 Vt[64 * 72];       // V^T tile [d][key^swz(d)], row stride 72
    __shared__ __align__(16) f16 Pw[4][16 * 72];    // per-wave P tile [q][key], row stride 72
    const int tid  = threadIdx.x;
    const int w    = tid >> 6;
    const int lane = tid & 63;
    const int b  = blockIdx.z, h = blockIdx.y;
    const int qt = (gridDim.x - 1) - blockIdx.x;    // descending tile order
    const int q0w = qt * 64 + w * 16;               // first query of this wave
    const int g  = lane >> 4;                       // 4 lane-groups
    const int lm = lane & 15;

    // Q fragments (held in registers for whole kernel)
    const long qrow = ((long)(b * T_ + q0w + lm)) * (3 * D_) + h * DH_;
    f16x8 af_q[2];
    af_q[0] = *(const f16x8*)(qkv + qrow + g * 8);
    af_q[1] = *(const f16x8*)(qkv + qrow + 32 + g * 8);

    float m_r[4], l_r[4];
    fx4 acc_o[4] = {};     // acc_o[nt][r]: out rows q0w+g*4+r, cols nt*16+lm
#pragma unroll
    for (int r = 0; r < 4; ++r) { m_r[r] = -INFINITY; l_r[r] = 0.0f; }

    // K staging coords: 4 threads per key row, each loads 32B (16 f16)
    const int srow = tid >> 2;          // key 0..63 within tile
    const int scol = (tid & 3) * 16;    // d col 0,16,32,48
    const long kbase = ((long)(b * T_)) * (3 * D_) + D_ + h * DH_ + scol;
    // V staging coords: thread owns key pair (2*vm, 2*vm+1) x 8 d-values
    const int vm  = tid >> 3;           // key pair 0..31
    const int vd0 = (tid & 7) * 8;      // d block 0..56
    const long vbase = ((long)(b * T_)) * (3 * D_) + 2 * D_ + h * DH_ + vd0;

    // prologue: load tile 0 into registers
    f16x8 kr0, kr1, vr0, vr1;
    {
        const f16* ks = qkv + kbase + (long)srow * (3 * D_);
        kr0 = *(const f16x8*)(ks);
        kr1 = *(const f16x8*)(ks + 8);
        const f16* va = qkv + vbase + (long)(2 * vm) * (3 * D_);
        vr0 = *(const f16x8*)(va);
        vr1 = *(const f16x8*)(va + 3 * D_);
    }

    const int nkb = qt + 1;
    for (int it = 0; it < nkb; ++it) {
        const int kb = it * 64;
        __syncthreads();    // previous compute done before overwriting K/V tiles
        // write staged registers -> LDS
        *(f16x8*)&Ks[srow * 72 + scol]     = kr0;
        *(f16x8*)&Ks[srow * 72 + scol + 8] = kr1;
#pragma unroll
        for (int j = 0; j < 8; ++j) {
            const int d = vd0 + j;
            const int col = (2 * vm) ^ (((d >> 2) & 7) << 3);   // swz multiple of 8 -> pair stays adjacent
            f16x2 pr = { vr0[j], vr1[j] };
            *(f16x2*)&Vt[d * 72 + col] = pr;
        }
        __syncthreads();    // staging visible

        // T14: issue next tile's loads now; they land under the compute below
        if (it + 1 < nkb) {
            const int kb2 = kb + 64;
            const f16* ks = qkv + kbase + (long)(kb2 + srow) * (3 * D_);
            kr0 = *(const f16x8*)(ks);
            kr1 = *(const f16x8*)(ks + 8);
            const f16* va = qkv + vbase + (long)(kb2 + 2 * vm) * (3 * D_);
            vr0 = *(const f16x8*)(va);
            vr1 = *(const f16x8*)(va + 3 * D_);
        }

        // QK^T: S tiles (16q x 16k) for 4 key sub-tiles
        fx4 sc[4];
#pragma unroll
        for (int kt = 0; kt < 4; ++kt) {
            fx4 c = {};
#pragma unroll
            for (int kk = 0; kk < 2; ++kk) {
                f16x8 bf = *(const f16x8*)&Ks[(kt * 16 + lm) * 72 + kk * 32 + g * 8];
                c = __builtin_amdgcn_mfma_f32_16x16x32_f16(af_q[kk], bf, c, 0, 0, 0);
            }
            sc[kt] = c * 0.125f;   // SCALE = DH^-0.5
        }
        // causal mask only possible in the last key block (kb == qt*64)
        if (kb == qt * 64) {
#pragma unroll
            for (int kt = 0; kt < 4; ++kt) {
                const int key_g = kb + kt * 16 + lm;
#pragma unroll
                for (int r = 0; r < 4; ++r)
                    if (key_g > q0w + g * 4 + r) sc[kt][r] = -INFINITY;
            }
        }

        // online softmax; row q=(g*4+r) lives across the 16 lanes with same g
        float mnew[4], pscale[4];
#pragma unroll
        for (int r = 0; r < 4; ++r) {
            float tm = fmaxf(fmaxf(sc[0][r], sc[1][r]), fmaxf(sc[2][r], sc[3][r]));
#pragma unroll
            for (int off = 8; off; off >>= 1) tm = fmaxf(tm, __shfl_xor(tm, off, 64));
            mnew[r]   = fmaxf(m_r[r], tm);
            pscale[r] = __expf(m_r[r] - mnew[r]);   // 0 on first block (m=-inf)
        }
        float psum[4] = {};
#pragma unroll
        for (int kt = 0; kt < 4; ++kt) {
#pragma unroll
            for (int r = 0; r < 4; ++r) {
                const float p = __expf(sc[kt][r] - mnew[r]);   // masked -> 0
                sc[kt][r] = p;
                psum[r] += p;
            }
        }
#pragma unroll
        for (int r = 0; r < 4; ++r) {
#pragma unroll
            for (int off = 8; off; off >>= 1) psum[r] += __shfl_xor(psum[r], off, 64);
            l_r[r] = l_r[r] * pscale[r] + psum[r];
            m_r[r] = mnew[r];
        }
#pragma unroll
        for (int nt = 0; nt < 4; ++nt)
#pragma unroll
            for (int r = 0; r < 4; ++r) acc_o[nt][r] *= pscale[r];

        // P (C layout) -> per-wave LDS [q][key] -> A frags
        f16* P = Pw[w];
#pragma unroll
        for (int kt = 0; kt < 4; ++kt)
#pragma unroll
            for (int r = 0; r < 4; ++r)
                P[(g * 4 + r) * 72 + kt * 16 + lm] = (f16)sc[kt][r];

        // PV: out(16q x 64d) += P(16x64) @ V(64x64)
#pragma unroll
        for (int kc = 0; kc < 2; ++kc) {
            f16x8 ap = *(const f16x8*)&P[lm * 72 + kc * 32 + g * 8];
#pragma unroll
            for (int nt = 0; nt < 4; ++nt) {
                const int d = nt * 16 + lm;
                const int col = (kc * 32 + g * 8) ^ (((d >> 2) & 7) << 3);
                f16x8 bv = *(const f16x8*)&Vt[d * 72 + col];
                acc_o[nt] = __builtin_amdgcn_mfma_f32_16x16x32_f16(ap, bv, acc_o[nt], 0, 0, 0);
            }
        }
    }

    // epilogue: out[(b*T + q)*D + h*64 + nt*16 + lm] = acc / l
    const long obase = ((long)(b * T_ + q0w + g * 4)) * D_ + h * DH_ + lm;
#pragma unroll
    for (int r = 0; r < 4; ++r) {
        const float inv = 1.0f / l_r[r];
#pragma unroll
        for (int nt = 0; nt < 4; ++nt)
            out[obase + (long)r * D_ + nt * 16] = acc_o[nt][r] * inv;
    }
}

// ---------------- host orchestration ----------------
extern "C" void kernel_launch(void* const* d_in, const int* in_sizes, int n_in,
                              void* d_out, int out_size, void* d_ws, size_t ws_size,
                              hipStream_t stream) {
    const int*   x    = (const int*)d_in[0];
    const float* emb  = (const float*)d_in[1];
    const float* pos  = (const float*)d_in[2];
    const float* Wqkv = (const float*)d_in[3];
    const float* bqkv = (const float*)d_in[4];
    const float* Wo   = (const float*)d_in[5];
    const float* bo   = (const float*)d_in[6];
    const float* Wg   = (const float*)d_in[7];
    const float* bg   = (const float*)d_in[8];
    const float* ln1g = (const float*)d_in[9];
    const float* ln1b = (const float*)d_in[10];
    const float* W1   = (const float*)d_in[11];
    const float* b1   = (const float*)d_in[12];
    const float* W2   = (const float*)d_in[13];
    const float* b2   = (const float*)d_in[14];
    const float* ln2g = (const float*)d_in[15];
    const float* ln2b = (const float*)d_in[16];
    const float* lnfg = (const float*)d_in[17];
    const float* lnfb = (const float*)d_in[18];
    float* out = (float*)d_out;

    char* ws = (char*)d_ws;
    size_t off = 0;
    auto alloc = [&](size_t bytes) -> void* {
        off = (off + 255) & ~(size_t)255;
        void* p = ws + off;
        off += bytes;
        return p;
    };
    float* h    = (float*)alloc((size_t)M_ * D_ * 4);
    float* n1f  = (float*)alloc((size_t)M_ * D_ * 4);
    float* pred = (float*)alloc((size_t)M_ * D_ * 4);
    float* corr = (float*)alloc((size_t)M_ * D_ * 4);
    float* glin = (float*)alloc((size_t)M_ * D_ * 4);
    f16* qkvh  = (f16*)alloc((size_t)M_ * 3 * D_ * 2);
    f16* ab    = (f16*)alloc((size_t)M_ * D_ * 2);
    f16* catb  = (f16*)alloc((size_t)M_ * 2 * D_ * 2);
    f16* ffh   = (f16*)alloc((size_t)M_ * FF_ * 2);
    f16* embh  = (f16*)alloc((size_t)V_ * D_ * 2);
    f16* wqkvh = (f16*)alloc((size_t)L_ * 2 * 3 * D_ * D_ * 2);
    f16* woh   = (f16*)alloc((size_t)L_ * D_ * D_ * 2);
    f16* wgh   = (f16*)alloc((size_t)L_ * D_ * 2 * D_ * 2);
    f16* w1h   = (f16*)alloc((size_t)L_ * FF_ * D_ * 2);
    f16* w2h   = (f16*)alloc((size_t)L_ * D_ * FF_ * 2);

    auto cvt = [&](const float* src, f16* dst, long n) {
        f2h_k<<<dim3((unsigned)(n / 1024)), dim3(256), 0, stream>>>(src, dst);
    };
    cvt(emb,  embh,  (long)V_ * D_);
    cvt(Wqkv, wqkvh, (long)L_ * 2 * 3 * D_ * D_);
    cvt(Wo,   woh,   (long)L_ * D_ * D_);
    cvt(Wg,   wgh,   (long)L_ * D_ * 2 * D_);
    cvt(W1,   w1h,   (long)L_ * FF_ * D_);
    cvt(W2,   w2h,   (long)L_ * D_ * FF_);

    embed_k<<<dim3(M_), dim3(256), 0, stream>>>(x, emb, pos, h);

    auto gemm = [&](const f16* A, const f16* Wt, const float* bias, const float* resid,
                    float* Cf, f16* Ch, int N, int K, int gelu) {
        if (N <= 1024)
            gemm_bt<64><<<dim3(N / 64, M_ / 128), dim3(256), 0, stream>>>(A, Wt, bias, resid, Cf, Ch, N, K, gelu);
        else
            gemm_bt<128><<<dim3(N / 128, M_ / 128), dim3(256), 0, stream>>>(A, Wt, bias, resid, Cf, Ch, N, K, gelu);
    };

    for (int l = 0; l < L_; ++l) {
        ln_k<<<dim3(M_), 256, 0, stream>>>(h, ln1g + l * D_, ln1b + l * D_, n1f, ab);
        gemm(ab, wqkvh + (size_t)(l * 2 + 0) * 3 * D_ * D_, bqkv + (l * 2 + 0) * 3 * D_,
             nullptr, nullptr, qkvh, 3 * D_, D_, 0);
        fattn_k<<<dim3(T_ / 64, H_, B_), 256, 0, stream>>>(qkvh, pred);
        sub_k<<<dim3(M_ * D_ / 1024), 256, 0, stream>>>(n1f, pred, ab);
        gemm(ab, wqkvh + (size_t)(l * 2 + 1) * 3 * D_ * D_, bqkv + (l * 2 + 1) * 3 * D_,
             nullptr, nullptr, qkvh, 3 * D_, D_, 0);
        fattn_k<<<dim3(T_ / 64, H_, B_), 256, 0, stream>>>(qkvh, corr);
        cat_k<<<dim3(M_ * 2 * D_ / 1024), 256, 0, stream>>>(pred, corr, catb);
        gemm(catb, wgh + (size_t)l * D_ * 2 * D_, bg + l * D_, nullptr, glin, nullptr, D_, 2 * D_, 0);
        gate_k<<<dim3(M_ * D_ / 1024), 256, 0, stream>>>(pred, corr, glin, ab);
        gemm(ab, woh + (size_t)l * D_ * D_, bo + l * D_, h, h, nullptr, D_, D_, 0);
        ln_k<<<dim3(M_), 256, 0, stream>>>(h, ln2g + l * D_, ln2b + l * D_, nullptr, ab);
        gemm(ab, w1h + (size_t)l * FF_ * D_, b1 + l * FF_, nullptr, nullptr, ffh, FF_, D_, 1);
        gemm(ffh, w2h + (size_t)l * D_ * FF_, b2 + l * D_, h, h, nullptr, D_, FF_, 0);
    }
    ln_k<<<dim3(M_), 256, 0, stream>>>(h, lnfg, lnfb, nullptr, ab);
    gemm(ab, embh, nullptr, nullptr, out, nullptr, V_, D_, 0);
}

// Round 10
// 2149.409 us; speedup vs baseline: 4.4234x; 1.0237x over previous
//
#include <hip/hip_runtime.h>
#include <math.h>

#define D_  1024
#define T_  1024
#define B_  2
#define H_  16
#define DH_ 64
#define L_  4
#define FF_ 4096
#define V_  32000
#define M_  2048   // B*T tokens

typedef _Float16 f16;
typedef _Float16 f16x8 __attribute__((ext_vector_type(8)));
typedef _Float16 f16x4 __attribute__((ext_vector_type(4)));
typedef _Float16 f16x2 __attribute__((ext_vector_type(2)));
typedef float    fx4  __attribute__((ext_vector_type(4)));

// ---------------- fp32 -> fp16 convert (exact-size grid, n % 1024 == 0) ----------------
__global__ __launch_bounds__(256) void f2h_k(const float* __restrict__ in, f16* __restrict__ out) {
    const long i = ((long)blockIdx.x * 256 + threadIdx.x) * 4;
    const float4 v = *(const float4*)(in + i);
    f16x4 o = { (f16)v.x, (f16)v.y, (f16)v.z, (f16)v.w };
    *(f16x4*)(out + i) = o;
}

// ---------------- embedding + positional ----------------
__global__ __launch_bounds__(256) void embed_k(const int* __restrict__ x, const float* __restrict__ emb,
                                               const float* __restrict__ pos, float* __restrict__ h) {
    const long m = blockIdx.x;            // token row 0..2047
    const int  t = threadIdx.x;           // 256 threads * float4 = 1024 floats
    const long tok = x[m];
    const long pt  = m & (T_ - 1);        // m % T
    const float4 e = ((const float4*)(emb + tok * D_))[t];
    const float4 p = ((const float4*)(pos + pt * D_))[t];
    ((float4*)(h + m * D_))[t] = make_float4(e.x + p.x, e.y + p.y, e.z + p.z, e.w + p.w);
}

// ---------------- LayerNorm over D=1024; optional fp32 + fp16 outputs ----------------
__global__ __launch_bounds__(256) void ln_k(const float* __restrict__ x, const float* __restrict__ g,
                                            const float* __restrict__ b, float* __restrict__ of,
                                            f16* __restrict__ oh) {
    const long m = blockIdx.x;
    const int  t = threadIdx.x;
    const int  wave = t >> 6, lane = t & 63;
    __shared__ float red1[4], red2[4];
    const float4 v = ((const float4*)(x + m * D_))[t];
    float s = v.x + v.y + v.z + v.w;
#pragma unroll
    for (int off = 32; off; off >>= 1) s += __shfl_xor(s, off, 64);
    if (lane == 0) red1[wave] = s;
    __syncthreads();
    const float mean = (red1[0] + red1[1] + red1[2] + red1[3]) * (1.0f / 1024.0f);
    const float d0 = v.x - mean, d1 = v.y - mean, d2 = v.z - mean, d3 = v.w - mean;
    float s2 = d0 * d0 + d1 * d1 + d2 * d2 + d3 * d3;
#pragma unroll
    for (int off = 32; off; off >>= 1) s2 += __shfl_xor(s2, off, 64);
    if (lane == 0) red2[wave] = s2;
    __syncthreads();
    const float var  = (red2[0] + red2[1] + red2[2] + red2[3]) * (1.0f / 1024.0f);
    const float rstd = rsqrtf(var + 1e-5f);
    const float4 gv = ((const float4*)g)[t];
    const float4 bv = ((const float4*)b)[t];
    const float o0 = d0 * rstd * gv.x + bv.x;
    const float o1 = d1 * rstd * gv.y + bv.y;
    const float o2 = d2 * rstd * gv.z + bv.z;
    const float o3 = d3 * rstd * gv.w + bv.w;
    if (of) ((float4*)(of + m * D_))[t] = make_float4(o0, o1, o2, o3);
    if (oh) { f16x4 o = { (f16)o0, (f16)o1, (f16)o2, (f16)o3 }; *(f16x4*)(oh + m * D_ + t * 4) = o; }
}

// ---------------- elementwise helpers ----------------
__global__ __launch_bounds__(256) void sub_k(const float* __restrict__ a, const float* __restrict__ b,
                                             f16* __restrict__ o) {   // o = f16(a - b)
    const long i = ((long)blockIdx.x * 256 + threadIdx.x) * 4;
    const float4 va = *(const float4*)(a + i);
    const float4 vb = *(const float4*)(b + i);
    f16x4 o4 = { (f16)(va.x - vb.x), (f16)(va.y - vb.y), (f16)(va.z - vb.z), (f16)(va.w - vb.w) };
    *(f16x4*)(o + i) = o4;
}

__global__ __launch_bounds__(256) void cat_k(const float* __restrict__ p, const float* __restrict__ c,
                                             f16* __restrict__ o) {   // o[m, 0:1024]=p[m], o[m,1024:2048]=c[m]
    const long i = ((long)blockIdx.x * 256 + threadIdx.x) * 4;        // over 2048*2048
    const long m = i >> 11;
    const int  j = (int)(i & 2047);
    const float* src = (j < 1024) ? (p + m * 1024 + j) : (c + m * 1024 + (j - 1024));
    const float4 v = *(const float4*)src;
    f16x4 o4 = { (f16)v.x, (f16)v.y, (f16)v.z, (f16)v.w };
    *(f16x4*)(o + i) = o4;
}

__global__ __launch_bounds__(256) void gate_k(const float* __restrict__ p, const float* __restrict__ c,
                                              const float* __restrict__ gl, f16* __restrict__ o) {
    // o = f16(pred + sigmoid(glin) * corr)
    const long i = ((long)blockIdx.x * 256 + threadIdx.x) * 4;
    const float4 vp = *(const float4*)(p + i);
    const float4 vc = *(const float4*)(c + i);
    const float4 vg = *(const float4*)(gl + i);
    const float s0 = 1.0f / (1.0f + __expf(-vg.x));
    const float s1 = 1.0f / (1.0f + __expf(-vg.y));
    const float s2 = 1.0f / (1.0f + __expf(-vg.z));
    const float s3 = 1.0f / (1.0f + __expf(-vg.w));
    f16x4 o4 = { (f16)(vp.x + s0 * vc.x), (f16)(vp.y + s1 * vc.y),
                 (f16)(vp.z + s2 * vc.z), (f16)(vp.w + s3 * vc.w) };
    *(f16x4*)(o + i) = o4;
}

// ---------------- GEMM: C(M,N) = A(M,K) @ W(N,K)^T [+bias] [+resid] [gelu]; fp32 and/or f16 out ----------------
// 128xBN tile, BK=32, 4 waves 2x2, global_load_lds width=16 staging, triple-buffered K pipeline
// with counted vmcnt (round 4). LDS swizzle (round 8: bank conflicts 1.64e7 -> 0).
// Round 9: LDS-TRANSPOSED VECTOR EPILOGUE — was 64 scalar global_store_dword per thread
// (vocab GEMM: 65.5M VMEM ops ~= 107us of store issue at ~1 op/cyc/CU). Each wave round-trips
// 16x16 f32 sub-tiles through a private 1.3KB LDS scratch so threads own 4 consecutive
// columns -> 16x float4/f16x4 stores per thread (4x fewer VMEM ops), resid loads vectorized.
template<int BN>
__global__ __launch_bounds__(256)
void gemm_bt(const f16* __restrict__ A, const f16* __restrict__ Wt,
             const float* __restrict__ bias, const float* __restrict__ resid,
             float* __restrict__ Cf, f16* __restrict__ Ch,
             int N, int K, int gelu) {
    __shared__ __align__(16) f16 As[3][128 * 32];
    __shared__ __align__(16) f16 Bs[3][BN * 32];
    const int tid  = threadIdx.x;
    const int wave = tid >> 6;
    const int lane = tid & 63;

    // block remap: linear id -> chunked XCD swizzle -> bm-fastest
    const int nbm = gridDim.y;           // M/128
    const int nbn = gridDim.x;           // N/BN
    int bi = blockIdx.y * nbn + blockIdx.x;
    const int nwg = nbm * nbn;
    if ((nwg & 7) == 0) bi = (bi & 7) * (nwg >> 3) + (bi >> 3);
    const long bm = bi % nbm;
    const long bn = bi / nbm;

    const int wm = (wave >> 1) * 64;
    const int wn = (wave & 1) * (BN / 2);
    constexpr int NJ = BN / 32;          // 4 for BN=128, 2 for BN=64

    fx4 acc[4][NJ] = {};

    // A staging: chunk c = wave*2 + {0,1}; lane covers row c*16 + lane/4,
    // col slot PRE-SWIZZLED: ((lane&3) ^ ((lane>>3)&3)) * 8
    const int c0 = wave * 2;
    const int r0 = c0 * 16 + (lane >> 2);
    const int cc = ((lane & 3) ^ ((lane >> 3) & 3)) * 8;
    const f16* a0 = A + ((long)bm * 128 + r0) * K + cc;
    const f16* a1 = A + ((long)bm * 128 + r0 + 16) * K + cc;

    const f16* b0;
    const f16* b1 = nullptr;
    if constexpr (BN == 128) {
        b0 = Wt + ((long)bn * 128 + r0) * K + cc;
        b1 = Wt + ((long)bn * 128 + r0 + 16) * K + cc;
    } else {  // BN == 64: one chunk per wave
        b0 = Wt + ((long)bn * 64 + wave * 16 + (lane >> 2)) * K + cc;
    }

    const int NT = K >> 5;               // K-tiles of 32

    auto STAGE = [&](int kt) {
        const int k0 = kt * 32;
        const int bf3 = kt % 3;
        __builtin_amdgcn_global_load_lds((const __attribute__((address_space(1))) void*)(a0 + k0),
                                         (__attribute__((address_space(3))) void*)&As[bf3][c0 * 512], 16, 0, 0);
        __builtin_amdgcn_global_load_lds((const __attribute__((address_space(1))) void*)(a1 + k0),
                                         (__attribute__((address_space(3))) void*)&As[bf3][(c0 + 1) * 512], 16, 0, 0);
        if constexpr (BN == 128) {
            __builtin_amdgcn_global_load_lds((const __attribute__((address_space(1))) void*)(b0 + k0),
                                             (__attribute__((address_space(3))) void*)&Bs[bf3][c0 * 512], 16, 0, 0);
            __builtin_amdgcn_global_load_lds((const __attribute__((address_space(1))) void*)(b1 + k0),
                                             (__attribute__((address_space(3))) void*)&Bs[bf3][(c0 + 1) * 512], 16, 0, 0);
        } else {
            __builtin_amdgcn_global_load_lds((const __attribute__((address_space(1))) void*)(b0 + k0),
                                             (__attribute__((address_space(3))) void*)&Bs[bf3][wave * 512], 16, 0, 0);
        }
    };

    // prologue: two K-tiles in flight before the loop
    STAGE(0);
    if (NT > 1) STAGE(1);

    const int lm = lane & 15;
    const int g  = lane >> 4;
    const int koff = (g ^ ((lm >> 1) & 3)) * 8;   // swizzled read offset
    for (int t = 0; t < NT; ++t) {
        if (t + 2 < NT) STAGE(t + 2);
        const int rem = NT - 1 - t;
        if constexpr (BN == 128) {       // L = 4 loads/thread/K-tile
            if (rem >= 2)      asm volatile("s_waitcnt vmcnt(8)" ::: "memory");
            else if (rem == 1) asm volatile("s_waitcnt vmcnt(4)" ::: "memory");
            else               asm volatile("s_waitcnt vmcnt(0)" ::: "memory");
        } else {                         // L = 3 loads/thread/K-tile
            if (rem >= 2)      asm volatile("s_waitcnt vmcnt(6)" ::: "memory");
            else if (rem == 1) asm volatile("s_waitcnt vmcnt(3)" ::: "memory");
            else               asm volatile("s_waitcnt vmcnt(0)" ::: "memory");
        }
        __builtin_amdgcn_s_barrier();            // all waves' batch-t loads landed
        __builtin_amdgcn_sched_barrier(0);

        const f16* as = As[t % 3];
        const f16* bs = Bs[t % 3];
        f16x8 af[4], bf[NJ];
#pragma unroll
        for (int i = 0; i < 4; ++i)
            af[i] = *(const f16x8*)&as[(wm + i * 16 + lm) * 32 + koff];
#pragma unroll
        for (int j = 0; j < NJ; ++j)
            bf[j] = *(const f16x8*)&bs[(wn + j * 16 + lm) * 32 + koff];
#pragma unroll
        for (int i = 0; i < 4; ++i)
#pragma unroll
            for (int j = 0; j < NJ; ++j)
                acc[i][j] = __builtin_amdgcn_mfma_f32_16x16x32_f16(af[i], bf[j], acc[i][j], 0, 0, 0);

        asm volatile("s_waitcnt lgkmcnt(0)" ::: "memory");   // ds_reads retired before release
        __builtin_amdgcn_sched_barrier(0);
        __builtin_amdgcn_s_barrier();            // buf[t%3] free for restage at t+1
    }

    // ---- epilogue: LDS-transposed vector stores ----
    // wave-private scratch: 16 rows x 20 f32 (pad 4 -> 16B-aligned rows) = 1280B
    float* esc = (float*)&As[0][0] + (size_t)wave * 320;
    const int erow = lane >> 2;          // 0..15
    const int ecg  = (lane & 3) * 4;     // col 0,4,8,12
    const long gr0 = bm * 128 + wm;
    const long gc0 = bn * BN + wn;
#pragma unroll
    for (int i = 0; i < 4; ++i) {
#pragma unroll
        for (int j = 0; j < NJ; ++j) {
#pragma unroll
            for (int r = 0; r < 4; ++r)
                esc[(g * 4 + r) * 20 + lm] = acc[i][j][r];
            asm volatile("s_waitcnt lgkmcnt(0)" ::: "memory");
            __builtin_amdgcn_sched_barrier(0);
            const fx4 q = *(const fx4*)&esc[erow * 20 + ecg];
            asm volatile("s_waitcnt lgkmcnt(0)" ::: "memory");
            __builtin_amdgcn_sched_barrier(0);
            const long row = gr0 + i * 16 + erow;
            const long col = gc0 + j * 16 + ecg;
            fx4 v = q;
            if (bias) {
                const fx4 b4 = *(const fx4*)&bias[col];
                v[0] += b4[0]; v[1] += b4[1]; v[2] += b4[2]; v[3] += b4[3];
            }
            if (gelu) {
#pragma unroll
                for (int e = 0; e < 4; ++e)
                    v[e] = 0.5f * v[e] * (1.0f + erff(v[e] * 0.70710678118654752f));
            } else if (resid) {
                const fx4 rz = *(const fx4*)&resid[row * (long)N + col];
                v[0] += rz[0]; v[1] += rz[1]; v[2] += rz[2]; v[3] += rz[3];
            }
            if (Cf) *(fx4*)&Cf[row * (long)N + col] = v;
            if (Ch) {
                f16x4 hq = { (f16)v[0], (f16)v[1], (f16)v[2], (f16)v[3] };
                *(f16x4*)&Ch[row * (long)N + col] = hq;
            }
        }
    }
}

// ---------------- flash attention: f16 QKV, fp32 softmax/accum, MFMA 16x16x32 ----------------
// qkv row layout (f16): [3][H][DH] per token. Block = 4 waves = 64 queries of one (b,h).
// grid: (T/64, H, B); big q-tiles launched first (qt descending).
// Round 9 (fixed): KVBLK=128 (halves per-iter barriers + shuffle-reduce chains) + per-wave
// diagonal clipping. K staging FIX vs round-8 draft: each thread now loads its FULL 32-f16
// slot (kr0..kr3) — the draft loaded only 16, leaving LDS cols 16-31/48-63 unwritten.
// Reg-prefetch (T14) and vectorized V^T scatter retained.
__global__ __launch_bounds__(256) void fattn_k(const f16* __restrict__ qkv, float* __restrict__ out) {
    __shared__ __align__(16) f16 Ks[128 * 72];      // K tile [key][d], row stride 72 (pad)
    __shared__ __align__(16) f16 Vt[64 * 136];      // V^T tile [d][key^swz(d)], row stride 136
    __shared__ __align__(16) f16 Pw[4][16 * 136];   // per-wave P tile [q][key], row stride 136
    const int tid  = threadIdx.x;
    const int w    = tid >> 6;
    const int lane = tid & 63;
    const int b  = blockIdx.z, h = blockIdx.y;
    const int qt = (gridDim.x - 1) - blockIdx.x;    // descending tile order
    const int q0w = qt * 64 + w * 16;               // first query of this wave
    const int g  = lane >> 4;                       // 4 lane-groups
    const int lm = lane & 15;

    // Q fragments (held in registers for whole kernel)
    const long qrow = ((long)(b * T_ + q0w + lm)) * (3 * D_) + h * DH_;
    f16x8 af_q[2];
    af_q[0] = *(const f16x8*)(qkv + qrow + g * 8);
    af_q[1] = *(const f16x8*)(qkv + qrow + 32 + g * 8);

    float m_r[4], l_r[4];
    fx4 acc_o[4] = {};     // acc_o[nt][r]: out rows q0w+g*4+r, cols nt*16+lm
#pragma unroll
    for (int r = 0; r < 4; ++r) { m_r[r] = -INFINITY; l_r[r] = 0.0f; }

    // K staging: thread -> key krow = tid>>1 (0..127), d half kdh = (tid&1)*32 (32 f16 slot)
    const int krow = tid >> 1;
    const int kdh  = (tid & 1) * 32;
    const long kbase = ((long)(b * T_)) * (3 * D_) + D_ + h * DH_ + kdh;
    // V staging: thread -> key pair (2*vm, 2*vm+1), d block vd0 = (tid&3)*16
    const int vm  = tid >> 2;           // 0..63
    const int vd0 = (tid & 3) * 16;     // 0,16,32,48
    const long vbase = ((long)(b * T_)) * (3 * D_) + 2 * D_ + h * DH_ + vd0;

    const int nit = (qt >> 1) + 1;      // 128-key iterations

    // prologue: load tile 0 into registers
    f16x8 kr0, kr1, kr2, kr3, vr0, vr1, vr2, vr3;
    {
        const f16* ks = qkv + kbase + (long)krow * (3 * D_);
        kr0 = *(const f16x8*)(ks);
        kr1 = *(const f16x8*)(ks + 8);
        kr2 = *(const f16x8*)(ks + 16);
        kr3 = *(const f16x8*)(ks + 24);
        const f16* va = qkv + vbase + (long)(2 * vm) * (3 * D_);
        vr0 = *(const f16x8*)(va);
        vr1 = *(const f16x8*)(va + 8);
        vr2 = *(const f16x8*)(va + 3 * D_);
        vr3 = *(const f16x8*)(va + 3 * D_ + 8);
    }

    for (int it = 0; it < nit; ++it) {
        const int kb = it * 128;
        __syncthreads();    // previous compute done before overwriting K/V tiles
        // write staged registers -> LDS (full 32-f16 K slot)
        *(f16x8*)&Ks[krow * 72 + kdh]      = kr0;
        *(f16x8*)&Ks[krow * 72 + kdh + 8]  = kr1;
        *(f16x8*)&Ks[krow * 72 + kdh + 16] = kr2;
        *(f16x8*)&Ks[krow * 72 + kdh + 24] = kr3;
#pragma unroll
        for (int jj = 0; jj < 16; ++jj) {
            const int d = vd0 + jj;
            const f16 va_ = (jj < 8) ? vr0[jj] : vr1[jj - 8];
            const f16 vb_ = (jj < 8) ? vr2[jj] : vr3[jj - 8];
            const int col = (2 * vm) ^ (((d >> 2) & 7) << 3);   // swz mult of 8 -> pair adjacent
            f16x2 pr = { va_, vb_ };
            *(f16x2*)&Vt[d * 136 + col] = pr;
        }
        __syncthreads();    // staging visible

        // T14: issue next tile's loads now; they land under the compute below
        if (it + 1 < nit) {
            const int kb2 = kb + 128;
            const f16* ks = qkv + kbase + (long)(kb2 + krow) * (3 * D_);
            kr0 = *(const f16x8*)(ks);
            kr1 = *(const f16x8*)(ks + 8);
            kr2 = *(const f16x8*)(ks + 16);
            kr3 = *(const f16x8*)(ks + 24);
            const f16* va = qkv + vbase + (long)(kb2 + 2 * vm) * (3 * D_);
            vr0 = *(const f16x8*)(va);
            vr1 = *(const f16x8*)(va + 8);
            vr2 = *(const f16x8*)(va + 3 * D_);
            vr3 = *(const f16x8*)(va + 3 * D_ + 8);
        }

        // per-wave active-key clipping
        const int qmax = q0w + 15;
        int nact = qmax - kb + 1; if (nact > 128) nact = 128;   // always >= 16
        const int nkt = (nact + 15) >> 4;   // active 16-key QK tiles (1..8)
        const int nkc = (nact + 31) >> 5;   // active 32-key PV chunks (1..4)
        const bool diag = (kb + 127 > q0w);

        // QK^T over active tiles
        fx4 sc[8];
#pragma unroll
        for (int kt = 0; kt < 8; ++kt) {
            if (kt < nkt) {
                fx4 c = {};
#pragma unroll
                for (int kk = 0; kk < 2; ++kk) {
                    f16x8 bf = *(const f16x8*)&Ks[(kt * 16 + lm) * 72 + kk * 32 + g * 8];
                    c = __builtin_amdgcn_mfma_f32_16x16x32_f16(af_q[kk], bf, c, 0, 0, 0);
                }
                c *= 0.125f;   // SCALE = DH^-0.5
                if (diag) {
                    const int key_g = kb + kt * 16 + lm;
#pragma unroll
                    for (int r = 0; r < 4; ++r)
                        if (key_g > q0w + g * 4 + r) c[r] = -INFINITY;
                }
                sc[kt] = c;
            }
        }

        // online softmax; row q=(g*4+r) lives across the 16 lanes with same g
        float mnew[4], pscale[4];
#pragma unroll
        for (int r = 0; r < 4; ++r) {
            float tm = -INFINITY;
#pragma unroll
            for (int kt = 0; kt < 8; ++kt)
                if (kt < nkt) tm = fmaxf(tm, sc[kt][r]);
#pragma unroll
            for (int off = 8; off; off >>= 1) tm = fmaxf(tm, __shfl_xor(tm, off, 64));
            mnew[r]   = fmaxf(m_r[r], tm);
            pscale[r] = __expf(m_r[r] - mnew[r]);   // 0 on first block (m=-inf)
        }
        float psum[4] = {};
#pragma unroll
        for (int kt = 0; kt < 8; ++kt) {
            if (kt < nkt) {
#pragma unroll
                for (int r = 0; r < 4; ++r) {
                    const float p = __expf(sc[kt][r] - mnew[r]);   // masked -> 0
                    sc[kt][r] = p;
                    psum[r] += p;
                }
            }
        }
#pragma unroll
        for (int r = 0; r < 4; ++r) {
#pragma unroll
            for (int off = 8; off; off >>= 1) psum[r] += __shfl_xor(psum[r], off, 64);
            l_r[r] = l_r[r] * pscale[r] + psum[r];
            m_r[r] = mnew[r];
        }
#pragma unroll
        for (int nt = 0; nt < 4; ++nt)
#pragma unroll
            for (int r = 0; r < 4; ++r) acc_o[nt][r] *= pscale[r];

        // P (C layout) -> per-wave LDS [q][key]; zero tile at kt==nkt (read by last PV chunk;
        // only executes when nkt <= 7, so index stays in bounds)
        f16* P = Pw[w];
#pragma unroll
        for (int kt = 0; kt < 8; ++kt) {
            if (kt < nkt) {
#pragma unroll
                for (int r = 0; r < 4; ++r)
                    P[(g * 4 + r) * 136 + kt * 16 + lm] = (f16)sc[kt][r];
            } else if (kt == nkt) {
#pragma unroll
                for (int r = 0; r < 4; ++r)
                    P[(g * 4 + r) * 136 + kt * 16 + lm] = (f16)0.0f;
            }
        }

        // PV over active chunks: out(16q x 64d) += P(16x128) @ V(128x64)
#pragma unroll
        for (int kc = 0; kc < 4; ++kc) {
            if (kc < nkc) {
                f16x8 ap = *(const f16x8*)&P[lm * 136 + kc * 32 + g * 8];
#pragma unroll
                for (int nt = 0; nt < 4; ++nt) {
                    const int d = nt * 16 + lm;
                    const int col = (kc * 32 + g * 8) ^ (((d >> 2) & 7) << 3);
                    f16x8 bv = *(const f16x8*)&Vt[d * 136 + col];
                    acc_o[nt] = __builtin_amdgcn_mfma_f32_16x16x32_f16(ap, bv, acc_o[nt], 0, 0, 0);
                }
            }
        }
    }

    // epilogue: out[(b*T + q)*D + h*64 + nt*16 + lm] = acc / l
    const long obase = ((long)(b * T_ + q0w + g * 4)) * D_ + h * DH_ + lm;
#pragma unroll
    for (int r = 0; r < 4; ++r) {
        const float inv = 1.0f / l_r[r];
#pragma unroll
        for (int nt = 0; nt < 4; ++nt)
            out[obase + (long)r * D_ + nt * 16] = acc_o[nt][r] * inv;
    }
}

// ---------------- host orchestration ----------------
extern "C" void kernel_launch(void* const* d_in, const int* in_sizes, int n_in,
                              void* d_out, int out_size, void* d_ws, size_t ws_size,
                              hipStream_t stream) {
    const int*   x    = (const int*)d_in[0];
    const float* emb  = (const float*)d_in[1];
    const float* pos  = (const float*)d_in[2];
    const float* Wqkv = (const float*)d_in[3];
    const float* bqkv = (const float*)d_in[4];
    const float* Wo   = (const float*)d_in[5];
    const float* bo   = (const float*)d_in[6];
    const float* Wg   = (const float*)d_in[7];
    const float* bg   = (const float*)d_in[8];
    const float* ln1g = (const float*)d_in[9];
    const float* ln1b = (const float*)d_in[10];
    const float* W1   = (const float*)d_in[11];
    const float* b1   = (const float*)d_in[12];
    const float* W2   = (const float*)d_in[13];
    const float* b2   = (const float*)d_in[14];
    const float* ln2g = (const float*)d_in[15];
    const float* ln2b = (const float*)d_in[16];
    const float* lnfg = (const float*)d_in[17];
    const float* lnfb = (const float*)d_in[18];
    float* out = (float*)d_out;

    char* ws = (char*)d_ws;
    size_t off = 0;
    auto alloc = [&](size_t bytes) -> void* {
        off = (off + 255) & ~(size_t)255;
        void* p = ws + off;
        off += bytes;
        return p;
    };
    float* h    = (float*)alloc((size_t)M_ * D_ * 4);
    float* n1f  = (float*)alloc((size_t)M_ * D_ * 4);
    float* pred = (float*)alloc((size_t)M_ * D_ * 4);
    float* corr = (float*)alloc((size_t)M_ * D_ * 4);
    float* glin = (float*)alloc((size_t)M_ * D_ * 4);
    f16* qkvh  = (f16*)alloc((size_t)M_ * 3 * D_ * 2);
    f16* ab    = (f16*)alloc((size_t)M_ * D_ * 2);
    f16* catb  = (f16*)alloc((size_t)M_ * 2 * D_ * 2);
    f16* ffh   = (f16*)alloc((size_t)M_ * FF_ * 2);
    f16* embh  = (f16*)alloc((size_t)V_ * D_ * 2);
    f16* wqkvh = (f16*)alloc((size_t)L_ * 2 * 3 * D_ * D_ * 2);
    f16* woh   = (f16*)alloc((size_t)L_ * D_ * D_ * 2);
    f16* wgh   = (f16*)alloc((size_t)L_ * D_ * 2 * D_ * 2);
    f16* w1h   = (f16*)alloc((size_t)L_ * FF_ * D_ * 2);
    f16* w2h   = (f16*)alloc((size_t)L_ * D_ * FF_ * 2);

    auto cvt = [&](const float* src, f16* dst, long n) {
        f2h_k<<<dim3((unsigned)(n / 1024)), dim3(256), 0, stream>>>(src, dst);
    };
    cvt(emb,  embh,  (long)V_ * D_);
    cvt(Wqkv, wqkvh, (long)L_ * 2 * 3 * D_ * D_);
    cvt(Wo,   woh,   (long)L_ * D_ * D_);
    cvt(Wg,   wgh,   (long)L_ * D_ * 2 * D_);
    cvt(W1,   w1h,   (long)L_ * FF_ * D_);
    cvt(W2,   w2h,   (long)L_ * D_ * FF_);

    embed_k<<<dim3(M_), dim3(256), 0, stream>>>(x, emb, pos, h);

    auto gemm = [&](const f16* A, const f16* Wt, const float* bias, const float* resid,
                    float* Cf, f16* Ch, int N, int K, int gelu) {
        if (N <= 1024)
            gemm_bt<64><<<dim3(N / 64, M_ / 128), dim3(256), 0, stream>>>(A, Wt, bias, resid, Cf, Ch, N, K, gelu);
        else
            gemm_bt<128><<<dim3(N / 128, M_ / 128), dim3(256), 0, stream>>>(A, Wt, bias, resid, Cf, Ch, N, K, gelu);
    };

    for (int l = 0; l < L_; ++l) {
        ln_k<<<dim3(M_), 256, 0, stream>>>(h, ln1g + l * D_, ln1b + l * D_, n1f, ab);
        gemm(ab, wqkvh + (size_t)(l * 2 + 0) * 3 * D_ * D_, bqkv + (l * 2 + 0) * 3 * D_,
             nullptr, nullptr, qkvh, 3 * D_, D_, 0);
        fattn_k<<<dim3(T_ / 64, H_, B_), 256, 0, stream>>>(qkvh, pred);
        sub_k<<<dim3(M_ * D_ / 1024), 256, 0, stream>>>(n1f, pred, ab);
        gemm(ab, wqkvh + (size_t)(l * 2 + 1) * 3 * D_ * D_, bqkv + (l * 2 + 1) * 3 * D_,
             nullptr, nullptr, qkvh, 3 * D_, D_, 0);
        fattn_k<<<dim3(T_ / 64, H_, B_), 256, 0, stream>>>(qkvh, corr);
        cat_k<<<dim3(M_ * 2 * D_ / 1024), 256, 0, stream>>>(pred, corr, catb);
        gemm(catb, wgh + (size_t)l * D_ * 2 * D_, bg + l * D_, nullptr, glin, nullptr, D_, 2 * D_, 0);
        gate_k<<<dim3(M_ * D_ / 1024), 256, 0, stream>>>(pred, corr, glin, ab);
        gemm(ab, woh + (size_t)l * D_ * D_, bo + l * D_, h, h, nullptr, D_, D_, 0);
        ln_k<<<dim3(M_), 256, 0, stream>>>(h, ln2g + l * D_, ln2b + l * D_, nullptr, ab);
        gemm(ab, w1h + (size_t)l * FF_ * D_, b1 + l * FF_, nullptr, nullptr, ffh, FF_, D_, 1);
        gemm(ffh, w2h + (size_t)l * D_ * FF_, b2 + l * D_, h, h, nullptr, D_, FF_, 0);
    }
    ln_k<<<dim3(M_), 256, 0, stream>>>(h, lnfg, lnfb, nullptr, ab);
    gemm(ab, embh, nullptr, nullptr, out, nullptr, V_, D_, 0);
}

// Round 12
// 2109.938 us; speedup vs baseline: 4.5062x; 1.0187x over previous
//
#include <hip/hip_runtime.h>
#include <math.h>

#define D_  1024
#define T_  1024
#define B_  2
#define H_  16
#define DH_ 64
#define L_  4
#define FF_ 4096
#define V_  32000
#define M_  2048   // B*T tokens

typedef _Float16 f16;
typedef _Float16 f16x8 __attribute__((ext_vector_type(8)));
typedef _Float16 f16x4 __attribute__((ext_vector_type(4)));
typedef _Float16 f16x2 __attribute__((ext_vector_type(2)));
typedef float    fx4  __attribute__((ext_vector_type(4)));

// ---------------- fp32 -> fp16 convert (exact-size grid, n % 1024 == 0) ----------------
__global__ __launch_bounds__(256) void f2h_k(const float* __restrict__ in, f16* __restrict__ out) {
    const long i = ((long)blockIdx.x * 256 + threadIdx.x) * 4;
    const float4 v = *(const float4*)(in + i);
    f16x4 o = { (f16)v.x, (f16)v.y, (f16)v.z, (f16)v.w };
    *(f16x4*)(out + i) = o;
}

// ---------------- embedding + positional ----------------
__global__ __launch_bounds__(256) void embed_k(const int* __restrict__ x, const float* __restrict__ emb,
                                               const float* __restrict__ pos, float* __restrict__ h) {
    const long m = blockIdx.x;            // token row 0..2047
    const int  t = threadIdx.x;           // 256 threads * float4 = 1024 floats
    const long tok = x[m];
    const long pt  = m & (T_ - 1);        // m % T
    const float4 e = ((const float4*)(emb + tok * D_))[t];
    const float4 p = ((const float4*)(pos + pt * D_))[t];
    ((float4*)(h + m * D_))[t] = make_float4(e.x + p.x, e.y + p.y, e.z + p.z, e.w + p.w);
}

// ---------------- LayerNorm over D=1024; optional fp32 + fp16 outputs ----------------
__global__ __launch_bounds__(256) void ln_k(const float* __restrict__ x, const float* __restrict__ g,
                                            const float* __restrict__ b, float* __restrict__ of,
                                            f16* __restrict__ oh) {
    const long m = blockIdx.x;
    const int  t = threadIdx.x;
    const int  wave = t >> 6, lane = t & 63;
    __shared__ float red1[4], red2[4];
    const float4 v = ((const float4*)(x + m * D_))[t];
    float s = v.x + v.y + v.z + v.w;
#pragma unroll
    for (int off = 32; off; off >>= 1) s += __shfl_xor(s, off, 64);
    if (lane == 0) red1[wave] = s;
    __syncthreads();
    const float mean = (red1[0] + red1[1] + red1[2] + red1[3]) * (1.0f / 1024.0f);
    const float d0 = v.x - mean, d1 = v.y - mean, d2 = v.z - mean, d3 = v.w - mean;
    float s2 = d0 * d0 + d1 * d1 + d2 * d2 + d3 * d3;
#pragma unroll
    for (int off = 32; off; off >>= 1) s2 += __shfl_xor(s2, off, 64);
    if (lane == 0) red2[wave] = s2;
    __syncthreads();
    const float var  = (red2[0] + red2[1] + red2[2] + red2[3]) * (1.0f / 1024.0f);
    const float rstd = rsqrtf(var + 1e-5f);
    const float4 gv = ((const float4*)g)[t];
    const float4 bv = ((const float4*)b)[t];
    const float o0 = d0 * rstd * gv.x + bv.x;
    const float o1 = d1 * rstd * gv.y + bv.y;
    const float o2 = d2 * rstd * gv.z + bv.z;
    const float o3 = d3 * rstd * gv.w + bv.w;
    if (of) ((float4*)(of + m * D_))[t] = make_float4(o0, o1, o2, o3);
    if (oh) { f16x4 o = { (f16)o0, (f16)o1, (f16)o2, (f16)o3 }; *(f16x4*)(oh + m * D_ + t * 4) = o; }
}

// ---------------- elementwise helper (cat only; sub/gate fused away) ----------------
__global__ __launch_bounds__(256) void cat_k(const float* __restrict__ p, const float* __restrict__ c,
                                             f16* __restrict__ o) {   // o[m, 0:1024]=p[m], o[m,1024:2048]=c[m]
    const long i = ((long)blockIdx.x * 256 + threadIdx.x) * 4;        // over 2048*2048
    const long m = i >> 11;
    const int  j = (int)(i & 2047);
    const float* src = (j < 1024) ? (p + m * 1024 + j) : (c + m * 1024 + (j - 1024));
    const float4 v = *(const float4*)src;
    f16x4 o4 = { (f16)v.x, (f16)v.y, (f16)v.z, (f16)v.w };
    *(f16x4*)(o + i) = o4;
}

// ---------------- GEMM: C(M,N) = A(M,K) @ W(N,K)^T [+bias] [+resid] [gelu] [gate]; fp32/f16 out ----------------
// 128xBN tile, BK=32, 4 waves 2x2, global_load_lds width=16 staging.
// Round 11: DOUBLE buffer (was triple). LDS 48->32KB (BN=128) / 24KB (BN=64) -> occupancy
// 2.4 -> ~5 blocks/CU. Prior rounds showed no single pipe >30% busy (MfmaUtil 24, LDS swizzled
// to 0 conflicts, HBM 21%) => latency/sync-bound at low concurrency; LDS footprint was the cap.
// Prefetch depth 2->1: HBM latency ~900cyc < 1 iteration period, so depth 1 suffices.
// Counted vmcnt (never 0 mid-loop), raw s_barrier, LDS swizzle, XCD block remap retained.
// gate_corr mode: Ch = f16(resid + sigmoid(acc+bias)*gate_corr)  [fuses old gate_k].
template<int BN>
__global__ __launch_bounds__(256)
void gemm_bt(const f16* __restrict__ A, const f16* __restrict__ Wt,
             const float* __restrict__ bias, const float* __restrict__ resid,
             const float* __restrict__ gate_corr,
             float* __restrict__ Cf, f16* __restrict__ Ch,
             int N, int K, int gelu) {
    __shared__ __align__(16) f16 As[2][128 * 32];
    __shared__ __align__(16) f16 Bs[2][BN * 32];
    const int tid  = threadIdx.x;
    const int wave = tid >> 6;
    const int lane = tid & 63;

    // block remap: linear id -> chunked XCD swizzle -> bm-fastest
    const int nbm = gridDim.y;           // M/128
    const int nbn = gridDim.x;           // N/BN
    int bi = blockIdx.y * nbn + blockIdx.x;
    const int nwg = nbm * nbn;
    if ((nwg & 7) == 0) bi = (bi & 7) * (nwg >> 3) + (bi >> 3);
    const long bm = bi % nbm;
    const long bn = bi / nbm;

    const int wm = (wave >> 1) * 64;
    const int wn = (wave & 1) * (BN / 2);
    constexpr int NJ = BN / 32;          // 4 for BN=128, 2 for BN=64

    fx4 acc[4][NJ] = {};

    // A staging: chunk c = wave*2 + {0,1}; lane covers row c*16 + lane/4,
    // col slot PRE-SWIZZLED: ((lane&3) ^ ((lane>>3)&3)) * 8
    const int c0 = wave * 2;
    const int r0 = c0 * 16 + (lane >> 2);
    const int cc = ((lane & 3) ^ ((lane >> 3) & 3)) * 8;
    const f16* a0 = A + ((long)bm * 128 + r0) * K + cc;
    const f16* a1 = A + ((long)bm * 128 + r0 + 16) * K + cc;

    const f16* b0;
    const f16* b1 = nullptr;
    if constexpr (BN == 128) {
        b0 = Wt + ((long)bn * 128 + r0) * K + cc;
        b1 = Wt + ((long)bn * 128 + r0 + 16) * K + cc;
    } else {  // BN == 64: one chunk per wave
        b0 = Wt + ((long)bn * 64 + wave * 16 + (lane >> 2)) * K + cc;
    }

    const int NT = K >> 5;               // K-tiles of 32

    auto STAGE = [&](int kt) {
        const int k0 = kt * 32;
        const int bf2 = kt & 1;
        __builtin_amdgcn_global_load_lds((const __attribute__((address_space(1))) void*)(a0 + k0),
                                         (__attribute__((address_space(3))) void*)&As[bf2][c0 * 512], 16, 0, 0);
        __builtin_amdgcn_global_load_lds((const __attribute__((address_space(1))) void*)(a1 + k0),
                                         (__attribute__((address_space(3))) void*)&As[bf2][(c0 + 1) * 512], 16, 0, 0);
        if constexpr (BN == 128) {
            __builtin_amdgcn_global_load_lds((const __attribute__((address_space(1))) void*)(b0 + k0),
                                             (__attribute__((address_space(3))) void*)&Bs[bf2][c0 * 512], 16, 0, 0);
            __builtin_amdgcn_global_load_lds((const __attribute__((address_space(1))) void*)(b1 + k0),
                                             (__attribute__((address_space(3))) void*)&Bs[bf2][(c0 + 1) * 512], 16, 0, 0);
        } else {
            __builtin_amdgcn_global_load_lds((const __attribute__((address_space(1))) void*)(b0 + k0),
                                             (__attribute__((address_space(3))) void*)&Bs[bf2][wave * 512], 16, 0, 0);
        }
    };

    // prologue: tile 0 in flight
    STAGE(0);

    const int lm = lane & 15;
    const int g  = lane >> 4;
    const int koff = (g ^ ((lm >> 1) & 3)) * 8;   // swizzled read offset
    for (int t = 0; t < NT; ++t) {
        // stage t+1 into buf[(t+1)&1]: its readers (iter t-1) retired at the closing barrier
        const bool more = (t + 1 < NT);
        if (more) STAGE(t + 1);
        // counted wait: batch t landed; batch t+1 (L loads) stays in flight
        if constexpr (BN == 128) {
            if (more) asm volatile("s_waitcnt vmcnt(4)" ::: "memory");
            else      asm volatile("s_waitcnt vmcnt(0)" ::: "memory");
        } else {
            if (more) asm volatile("s_waitcnt vmcnt(3)" ::: "memory");
            else      asm volatile("s_waitcnt vmcnt(0)" ::: "memory");
        }
        __builtin_amdgcn_s_barrier();            // all waves' batch-t loads landed
        __builtin_amdgcn_sched_barrier(0);

        const f16* as = As[t & 1];
        const f16* bs = Bs[t & 1];
        f16x8 af[4], bf[NJ];
#pragma unroll
        for (int i = 0; i < 4; ++i)
            af[i] = *(const f16x8*)&as[(wm + i * 16 + lm) * 32 + koff];
#pragma unroll
        for (int j = 0; j < NJ; ++j)
            bf[j] = *(const f16x8*)&bs[(wn + j * 16 + lm) * 32 + koff];
#pragma unroll
        for (int i = 0; i < 4; ++i)
#pragma unroll
            for (int j = 0; j < NJ; ++j)
                acc[i][j] = __builtin_amdgcn_mfma_f32_16x16x32_f16(af[i], bf[j], acc[i][j], 0, 0, 0);

        asm volatile("s_waitcnt lgkmcnt(0)" ::: "memory");   // ds_reads retired before release
        __builtin_amdgcn_sched_barrier(0);
        __builtin_amdgcn_s_barrier();            // buf[t&1] free for restage at t+1
    }

    // ---- epilogue: LDS-transposed vector stores ----
    // wave-private scratch: 16 rows x 20 f32 (pad 4 -> 16B-aligned rows) = 1280B
    float* esc = (float*)&As[0][0] + (size_t)wave * 320;
    const int erow = lane >> 2;          // 0..15
    const int ecg  = (lane & 3) * 4;     // col 0,4,8,12
    const long gr0 = bm * 128 + wm;
    const long gc0 = bn * BN + wn;
#pragma unroll
    for (int i = 0; i < 4; ++i) {
#pragma unroll
        for (int j = 0; j < NJ; ++j) {
#pragma unroll
            for (int r = 0; r < 4; ++r)
                esc[(g * 4 + r) * 20 + lm] = acc[i][j][r];
            asm volatile("s_waitcnt lgkmcnt(0)" ::: "memory");
            __builtin_amdgcn_sched_barrier(0);
            const fx4 q = *(const fx4*)&esc[erow * 20 + ecg];
            asm volatile("s_waitcnt lgkmcnt(0)" ::: "memory");
            __builtin_amdgcn_sched_barrier(0);
            const long row = gr0 + i * 16 + erow;
            const long col = gc0 + j * 16 + ecg;
            fx4 v = q;
            if (bias) {
                const fx4 b4 = *(const fx4*)&bias[col];
                v[0] += b4[0]; v[1] += b4[1]; v[2] += b4[2]; v[3] += b4[3];
            }
            if (gate_corr) {
                // fused gate: out = pred(resid) + sigmoid(v) * corr
                const fx4 pz = *(const fx4*)&resid[row * (long)N + col];
                const fx4 cz = *(const fx4*)&gate_corr[row * (long)N + col];
#pragma unroll
                for (int e = 0; e < 4; ++e) {
                    const float s = 1.0f / (1.0f + __expf(-v[e]));
                    v[e] = pz[e] + s * cz[e];
                }
                f16x4 hq = { (f16)v[0], (f16)v[1], (f16)v[2], (f16)v[3] };
                *(f16x4*)&Ch[row * (long)N + col] = hq;
                continue;
            }
            if (gelu) {
#pragma unroll
                for (int e = 0; e < 4; ++e)
                    v[e] = 0.5f * v[e] * (1.0f + erff(v[e] * 0.70710678118654752f));
            } else if (resid) {
                const fx4 rz = *(const fx4*)&resid[row * (long)N + col];
                v[0] += rz[0]; v[1] += rz[1]; v[2] += rz[2]; v[3] += rz[3];
            }
            if (Cf) *(fx4*)&Cf[row * (long)N + col] = v;
            if (Ch) {
                f16x4 hq = { (f16)v[0], (f16)v[1], (f16)v[2], (f16)v[3] };
                *(f16x4*)&Ch[row * (long)N + col] = hq;
            }
        }
    }
}

// ---------------- flash attention: f16 QKV, fp32 softmax/accum, MFMA 16x16x32 ----------------
// qkv row layout (f16): [3][H][DH] per token. Block = 4 waves = 64 queries of one (b,h).
// grid: (T/64, H, B); big q-tiles launched first (qt descending).
// KVBLK=128, per-wave diagonal clipping, T14 reg-prefetch, vectorized V^T scatter (round 10).
// Round 11: fused sub — optional (n1, dif): dif = f16(n1 - out) written in epilogue.
__global__ __launch_bounds__(256) void fattn_k(const f16* __restrict__ qkv, float* __restrict__ out,
                                               const float* __restrict__ n1, f16* __restrict__ dif) {
    __shared__ __align__(16) f16 Ks[128 * 72];      // K tile [key][d], row stride 72 (pad)
    __shared__ __align__(16) f16 Vt[64 * 136];      // V^T tile [d][key^swz(d)], row stride 136
    __shared__ __align__(16) f16 Pw[4][16 * 136];   // per-wave P tile [q][key], row stride 136
    const int tid  = threadIdx.x;
    const int w    = tid >> 6;
    const int lane = tid & 63;
    const int b  = blockIdx.z, h = blockIdx.y;
    const int qt = (gridDim.x - 1) - blockIdx.x;    // descending tile order
    const int q0w = qt * 64 + w * 16;               // first query of this wave
    const int g  = lane >> 4;                       // 4 lane-groups
    const int lm = lane & 15;

    // Q fragments (held in registers for whole kernel)
    const long qrow = ((long)(b * T_ + q0w + lm)) * (3 * D_) + h * DH_;
    f16x8 af_q[2];
    af_q[0] = *(const f16x8*)(qkv + qrow + g * 8);
    af_q[1] = *(const f16x8*)(qkv + qrow + 32 + g * 8);

    float m_r[4], l_r[4];
    fx4 acc_o[4] = {};     // acc_o[nt][r]: out rows q0w+g*4+r, cols nt*16+lm
#pragma unroll
    for (int r = 0; r < 4; ++r) { m_r[r] = -INFINITY; l_r[r] = 0.0f; }

    // K staging: thread -> key krow = tid>>1 (0..127), d half kdh = (tid&1)*32 (32 f16 slot)
    const int krow = tid >> 1;
    const int kdh  = (tid & 1) * 32;
    const long kbase = ((long)(b * T_)) * (3 * D_) + D_ + h * DH_ + kdh;
    // V staging: thread -> key pair (2*vm, 2*vm+1), d block vd0 = (tid&3)*16
    const int vm  = tid >> 2;           // 0..63
    const int vd0 = (tid & 3) * 16;     // 0,16,32,48
    const long vbase = ((long)(b * T_)) * (3 * D_) + 2 * D_ + h * DH_ + vd0;

    const int nit = (qt >> 1) + 1;      // 128-key iterations

    // prologue: load tile 0 into registers
    f16x8 kr0, kr1, kr2, kr3, vr0, vr1, vr2, vr3;
    {
        const f16* ks = qkv + kbase + (long)krow * (3 * D_);
        kr0 = *(const f16x8*)(ks);
        kr1 = *(const f16x8*)(ks + 8);
        kr2 = *(const f16x8*)(ks + 16);
        kr3 = *(const f16x8*)(ks + 24);
        const f16* va = qkv + vbase + (long)(2 * vm) * (3 * D_);
        vr0 = *(const f16x8*)(va);
        vr1 = *(const f16x8*)(va + 8);
        vr2 = *(const f16x8*)(va + 3 * D_);
        vr3 = *(const f16x8*)(va + 3 * D_ + 8);
    }

    for (int it = 0; it < nit; ++it) {
        const int kb = it * 128;
        __syncthreads();    // previous compute done before overwriting K/V tiles
        // write staged registers -> LDS (full 32-f16 K slot)
        *(f16x8*)&Ks[krow * 72 + kdh]      = kr0;
        *(f16x8*)&Ks[krow * 72 + kdh + 8]  = kr1;
        *(f16x8*)&Ks[krow * 72 + kdh + 16] = kr2;
        *(f16x8*)&Ks[krow * 72 + kdh + 24] = kr3;
#pragma unroll
        for (int jj = 0; jj < 16; ++jj) {
            const int d = vd0 + jj;
            const f16 va_ = (jj < 8) ? vr0[jj] : vr1[jj - 8];
            const f16 vb_ = (jj < 8) ? vr2[jj] : vr3[jj - 8];
            const int col = (2 * vm) ^ (((d >> 2) & 7) << 3);   // swz mult of 8 -> pair adjacent
            f16x2 pr = { va_, vb_ };
            *(f16x2*)&Vt[d * 136 + col] = pr;
        }
        __syncthreads();    // staging visible

        // T14: issue next tile's loads now; they land under the compute below
        if (it + 1 < nit) {
            const int kb2 = kb + 128;
            const f16* ks = qkv + kbase + (long)(kb2 + krow) * (3 * D_);
            kr0 = *(const f16x8*)(ks);
            kr1 = *(const f16x8*)(ks + 8);
            kr2 = *(const f16x8*)(ks + 16);
            kr3 = *(const f16x8*)(ks + 24);
            const f16* va = qkv + vbase + (long)(kb2 + 2 * vm) * (3 * D_);
            vr0 = *(const f16x8*)(va);
            vr1 = *(const f16x8*)(va + 8);
            vr2 = *(const f16x8*)(va + 3 * D_);
            vr3 = *(const f16x8*)(va + 3 * D_ + 8);
        }

        // per-wave active-key clipping
        const int qmax = q0w + 15;
        int nact = qmax - kb + 1; if (nact > 128) nact = 128;   // always >= 16
        const int nkt = (nact + 15) >> 4;   // active 16-key QK tiles (1..8)
        const int nkc = (nact + 31) >> 5;   // active 32-key PV chunks (1..4)
        const bool diag = (kb + 127 > q0w);

        // QK^T over active tiles
        fx4 sc[8];
#pragma unroll
        for (int kt = 0; kt < 8; ++kt) {
            if (kt < nkt) {
                fx4 c = {};
#pragma unroll
                for (int kk = 0; kk < 2; ++kk) {
                    f16x8 bf = *(const f16x8*)&Ks[(kt * 16 + lm) * 72 + kk * 32 + g * 8];
                    c = __builtin_amdgcn_mfma_f32_16x16x32_f16(af_q[kk], bf, c, 0, 0, 0);
                }
                c *= 0.125f;   // SCALE = DH^-0.5
                if (diag) {
                    const int key_g = kb + kt * 16 + lm;
#pragma unroll
                    for (int r = 0; r < 4; ++r)
                        if (key_g > q0w + g * 4 + r) c[r] = -INFINITY;
                }
                sc[kt] = c;
            }
        }

        // online softmax; row q=(g*4+r) lives across the 16 lanes with same g
        float mnew[4], pscale[4];
#pragma unroll
        for (int r = 0; r < 4; ++r) {
            float tm = -INFINITY;
#pragma unroll
            for (int kt = 0; kt < 8; ++kt)
                if (kt < nkt) tm = fmaxf(tm, sc[kt][r]);
#pragma unroll
            for (int off = 8; off; off >>= 1) tm = fmaxf(tm, __shfl_xor(tm, off, 64));
            mnew[r]   = fmaxf(m_r[r], tm);
            pscale[r] = __expf(m_r[r] - mnew[r]);   // 0 on first block (m=-inf)
        }
        float psum[4] = {};
#pragma unroll
        for (int kt = 0; kt < 8; ++kt) {
            if (kt < nkt) {
#pragma unroll
                for (int r = 0; r < 4; ++r) {
                    const float p = __expf(sc[kt][r] - mnew[r]);   // masked -> 0
                    sc[kt][r] = p;
                    psum[r] += p;
                }
            }
        }
#pragma unroll
        for (int r = 0; r < 4; ++r) {
#pragma unroll
            for (int off = 8; off; off >>= 1) psum[r] += __shfl_xor(psum[r], off, 64);
            l_r[r] = l_r[r] * pscale[r] + psum[r];
            m_r[r] = mnew[r];
        }
#pragma unroll
        for (int nt = 0; nt < 4; ++nt)
#pragma unroll
            for (int r = 0; r < 4; ++r) acc_o[nt][r] *= pscale[r];

        // P (C layout) -> per-wave LDS [q][key]; zero tile at kt==nkt (read by last PV chunk;
        // only executes when nkt <= 7, so index stays in bounds)
        f16* P = Pw[w];
#pragma unroll
        for (int kt = 0; kt < 8; ++kt) {
            if (kt < nkt) {
#pragma unroll
                for (int r = 0; r < 4; ++r)
                    P[(g * 4 + r) * 136 + kt * 16 + lm] = (f16)sc[kt][r];
            } else if (kt == nkt) {
#pragma unroll
                for (int r = 0; r < 4; ++r)
                    P[(g * 4 + r) * 136 + kt * 16 + lm] = (f16)0.0f;
            }
        }

        // PV over active chunks: out(16q x 64d) += P(16x128) @ V(128x64)
#pragma unroll
        for (int kc = 0; kc < 4; ++kc) {
            if (kc < nkc) {
                f16x8 ap = *(const f16x8*)&P[lm * 136 + kc * 32 + g * 8];
#pragma unroll
                for (int nt = 0; nt < 4; ++nt) {
                    const int d = nt * 16 + lm;
                    const int col = (kc * 32 + g * 8) ^ (((d >> 2) & 7) << 3);
                    f16x8 bv = *(const f16x8*)&Vt[d * 136 + col];
                    acc_o[nt] = __builtin_amdgcn_mfma_f32_16x16x32_f16(ap, bv, acc_o[nt], 0, 0, 0);
                }
            }
        }
    }

    // epilogue: out = acc / l; optional fused dif = f16(n1 - out)
    const long obase = ((long)(b * T_ + q0w + g * 4)) * D_ + h * DH_ + lm;
#pragma unroll
    for (int r = 0; r < 4; ++r) {
        const float inv = 1.0f / l_r[r];
#pragma unroll
        for (int nt = 0; nt < 4; ++nt) {
            const long idx = obase + (long)r * D_ + nt * 16;
            const float val = acc_o[nt][r] * inv;
            out[idx] = val;
            if (dif) dif[idx] = (f16)(n1[idx] - val);
        }
    }
}

// ---------------- host orchestration ----------------
extern "C" void kernel_launch(void* const* d_in, const int* in_sizes, int n_in,
                              void* d_out, int out_size, void* d_ws, size_t ws_size,
                              hipStream_t stream) {
    const int*   x    = (const int*)d_in[0];
    const float* emb  = (const float*)d_in[1];
    const float* pos  = (const float*)d_in[2];
    const float* Wqkv = (const float*)d_in[3];
    const float* bqkv = (const float*)d_in[4];
    const float* Wo   = (const float*)d_in[5];
    const float* bo   = (const float*)d_in[6];
    const float* Wg   = (const float*)d_in[7];
    const float* bg   = (const float*)d_in[8];
    const float* ln1g = (const float*)d_in[9];
    const float* ln1b = (const float*)d_in[10];
    const float* W1   = (const float*)d_in[11];
    const float* b1   = (const float*)d_in[12];
    const float* W2   = (const float*)d_in[13];
    const float* b2   = (const float*)d_in[14];
    const float* ln2g = (const float*)d_in[15];
    const float* ln2b = (const float*)d_in[16];
    const float* lnfg = (const float*)d_in[17];
    const float* lnfb = (const float*)d_in[18];
    float* out = (float*)d_out;

    char* ws = (char*)d_ws;
    size_t off = 0;
    auto alloc = [&](size_t bytes) -> void* {
        off = (off + 255) & ~(size_t)255;
        void* p = ws + off;
        off += bytes;
        return p;
    };
    float* h    = (float*)alloc((size_t)M_ * D_ * 4);
    float* n1f  = (float*)alloc((size_t)M_ * D_ * 4);
    float* pred = (float*)alloc((size_t)M_ * D_ * 4);
    float* corr = (float*)alloc((size_t)M_ * D_ * 4);
    f16* qkvh  = (f16*)alloc((size_t)M_ * 3 * D_ * 2);
    f16* ab    = (f16*)alloc((size_t)M_ * D_ * 2);
    f16* catb  = (f16*)alloc((size_t)M_ * 2 * D_ * 2);
    f16* ffh   = (f16*)alloc((size_t)M_ * FF_ * 2);
    f16* embh  = (f16*)alloc((size_t)V_ * D_ * 2);
    f16* wqkvh = (f16*)alloc((size_t)L_ * 2 * 3 * D_ * D_ * 2);
    f16* woh   = (f16*)alloc((size_t)L_ * D_ * D_ * 2);
    f16* wgh   = (f16*)alloc((size_t)L_ * D_ * 2 * D_ * 2);
    f16* w1h   = (f16*)alloc((size_t)L_ * FF_ * D_ * 2);
    f16* w2h   = (f16*)alloc((size_t)L_ * D_ * FF_ * 2);

    auto cvt = [&](const float* src, f16* dst, long n) {
        f2h_k<<<dim3((unsigned)(n / 1024)), dim3(256), 0, stream>>>(src, dst);
    };
    cvt(emb,  embh,  (long)V_ * D_);
    cvt(Wqkv, wqkvh, (long)L_ * 2 * 3 * D_ * D_);
    cvt(Wo,   woh,   (long)L_ * D_ * D_);
    cvt(Wg,   wgh,   (long)L_ * D_ * 2 * D_);
    cvt(W1,   w1h,   (long)L_ * FF_ * D_);
    cvt(W2,   w2h,   (long)L_ * D_ * FF_);

    embed_k<<<dim3(M_), dim3(256), 0, stream>>>(x, emb, pos, h);

    auto gemm = [&](const f16* A, const f16* Wt, const float* bias, const float* resid,
                    const float* gate_corr, float* Cf, f16* Ch, int N, int K, int gelu) {
        if (N <= 1024)
            gemm_bt<64><<<dim3(N / 64, M_ / 128), dim3(256), 0, stream>>>(A, Wt, bias, resid, gate_corr, Cf, Ch, N, K, gelu);
        else
            gemm_bt<128><<<dim3(N / 128, M_ / 128), dim3(256), 0, stream>>>(A, Wt, bias, resid, gate_corr, Cf, Ch, N, K, gelu);
    };

    for (int l = 0; l < L_; ++l) {
        ln_k<<<dim3(M_), 256, 0, stream>>>(h, ln1g + l * D_, ln1b + l * D_, n1f, ab);
        gemm(ab, wqkvh + (size_t)(l * 2 + 0) * 3 * D_ * D_, bqkv + (l * 2 + 0) * 3 * D_,
             nullptr, nullptr, nullptr, qkvh, 3 * D_, D_, 0);
        // fattn + fused sub: pred, ab = f16(n1f - pred)
        fattn_k<<<dim3(T_ / 64, H_, B_), 256, 0, stream>>>(qkvh, pred, n1f, ab);
        gemm(ab, wqkvh + (size_t)(l * 2 + 1) * 3 * D_ * D_, bqkv + (l * 2 + 1) * 3 * D_,
             nullptr, nullptr, nullptr, qkvh, 3 * D_, D_, 0);
        fattn_k<<<dim3(T_ / 64, H_, B_), 256, 0, stream>>>(qkvh, corr, nullptr, nullptr);
        cat_k<<<dim3(M_ * 2 * D_ / 1024), 256, 0, stream>>>(pred, corr, catb);
        // Wg GEMM + fused gate: ab = f16(pred + sigmoid(glin) * corr)
        gemm(catb, wgh + (size_t)l * D_ * 2 * D_, bg + l * D_, pred, corr, nullptr, ab, D_, 2 * D_, 0);
        gemm(ab, woh + (size_t)l * D_ * D_, bo + l * D_, h, nullptr, h, nullptr, D_, D_, 0);
        ln_k<<<dim3(M_), 256, 0, stream>>>(h, ln2g + l * D_, ln2b + l * D_, nullptr, ab);
        gemm(ab, w1h + (size_t)l * FF_ * D_, b1 + l * FF_, nullptr, nullptr, nullptr, ffh, FF_, D_, 1);
        gemm(ffh, w2h + (size_t)l * D_ * FF_, b2 + l * D_, h, nullptr, h, nullptr, D_, FF_, 0);
    }
    ln_k<<<dim3(M_), 256, 0, stream>>>(h, lnfg, lnfb, nullptr, ab);
    gemm(ab, embh, nullptr, nullptr, nullptr, out, nullptr, V_, D_, 0);
}